// Round 1
// baseline (1330.281 us; speedup 1.0000x reference)
//
#include <hip/hip_runtime.h>
#include <hip/hip_bf16.h>

// Problem constants (reference: HIDDEN=ATTN=1024, B=4, S=2048)
#define H    1024
#define SEQ  2048
#define NB   4
#define MTOT (NB * SEQ)   // 8192

// ---------------------------------------------------------------------------
// Tiled fp32 GEMM: C[M,N] = A[M,K] @ op(B) + bias
//   TRANSB=false: B is [K,N] row-major (NN)
//   TRANSB=true : B is [N,K] row-major, C = A @ B^T (NT)
// 128x128 tile, BK=16, 256 threads, 8x8 register microtile.
// blockIdx.z batches with element strides sA/sB/sC.
// All problem dims divide the tile sizes exactly (1024/2048 % 128 == 0,
// K % 16 == 0) so no bounds checks.
// ---------------------------------------------------------------------------
template<bool TRANSB, bool BIAS>
__global__ __launch_bounds__(256)
void gemm_f32(const float* __restrict__ A, const float* __restrict__ Bm,
              const float* __restrict__ bias, float* __restrict__ C,
              int M, int N, int K, long sA, long sB, long sC)
{
    // +4 pad on the 128-wide leading dim: breaks power-of-2 bank strides
    __shared__ float As[16][132];   // stored transposed: As[k][m]
    __shared__ float Bs[16][132];   // stored as Bs[k][n]

    A  += (long)blockIdx.z * sA;
    Bm += (long)blockIdx.z * sB;
    C  += (long)blockIdx.z * sC;

    const int t  = threadIdx.x;
    const int m0 = blockIdx.y << 7;
    const int n0 = blockIdx.x << 7;
    const int tr = t >> 4;          // 0..15 -> rows tr*8..tr*8+7
    const int tc = t & 15;          // 0..15 -> cols tc*8..tc*8+7

    float acc[8][8];
#pragma unroll
    for (int i = 0; i < 8; ++i)
#pragma unroll
        for (int j = 0; j < 8; ++j) acc[i][j] = 0.f;

    for (int k0 = 0; k0 < K; k0 += 16) {
        // ---- stage tiles: 128x16 each = 512 float4, 2 per thread ----
#pragma unroll
        for (int u = 0; u < 2; ++u) {
            const int f   = t + (u << 8);
            const int row = f >> 2;             // 0..127
            const int kg  = (f & 3) << 2;       // 0,4,8,12
            float4 av = *(const float4*)&A[(long)(m0 + row) * K + k0 + kg];
            As[kg + 0][row] = av.x; As[kg + 1][row] = av.y;
            As[kg + 2][row] = av.z; As[kg + 3][row] = av.w;
            if (TRANSB) {
                float4 bv = *(const float4*)&Bm[(long)(n0 + row) * K + k0 + kg];
                Bs[kg + 0][row] = bv.x; Bs[kg + 1][row] = bv.y;
                Bs[kg + 2][row] = bv.z; Bs[kg + 3][row] = bv.w;
            } else {
                const int kr = f >> 5;          // 0..15
                const int nc = (f & 31) << 2;   // 0..124
                *(float4*)&Bs[kr][nc] =
                    *(const float4*)&Bm[(long)(k0 + kr) * N + n0 + nc];
            }
        }
        __syncthreads();

        // ---- 8x8 outer-product microkernel ----
#pragma unroll
        for (int kk = 0; kk < 16; ++kk) {
            float4 a0 = *(const float4*)&As[kk][tr << 3];
            float4 a1 = *(const float4*)&As[kk][(tr << 3) + 4];
            float4 b0 = *(const float4*)&Bs[kk][tc << 3];
            float4 b1 = *(const float4*)&Bs[kk][(tc << 3) + 4];
            float a[8] = {a0.x, a0.y, a0.z, a0.w, a1.x, a1.y, a1.z, a1.w};
            float b[8] = {b0.x, b0.y, b0.z, b0.w, b1.x, b1.y, b1.z, b1.w};
#pragma unroll
            for (int i = 0; i < 8; ++i)
#pragma unroll
                for (int j = 0; j < 8; ++j) acc[i][j] += a[i] * b[j];
        }
        __syncthreads();
    }

    float bb[8] = {0, 0, 0, 0, 0, 0, 0, 0};
    if (BIAS) {
        float4 t0 = *(const float4*)&bias[n0 + (tc << 3)];
        float4 t1 = *(const float4*)&bias[n0 + (tc << 3) + 4];
        bb[0] = t0.x; bb[1] = t0.y; bb[2] = t0.z; bb[3] = t0.w;
        bb[4] = t1.x; bb[5] = t1.y; bb[6] = t1.z; bb[7] = t1.w;
    }
#pragma unroll
    for (int i = 0; i < 8; ++i) {
        float* cp = &C[(long)(m0 + (tr << 3) + i) * N + n0 + (tc << 3)];
        float4 o0 = make_float4(acc[i][0] + bb[0], acc[i][1] + bb[1],
                                acc[i][2] + bb[2], acc[i][3] + bb[3]);
        float4 o1 = make_float4(acc[i][4] + bb[4], acc[i][5] + bb[5],
                                acc[i][6] + bb[6], acc[i][7] + bb[7]);
        *(float4*)cp = o0;
        *(float4*)(cp + 4) = o1;
    }
}

// ---------------------------------------------------------------------------
// Row softmax, in place. One block per row of 2048. 256 threads x 8 elems.
// ---------------------------------------------------------------------------
__global__ __launch_bounds__(256)
void softmax_rows(float* __restrict__ S)
{
    float* p = S + (long)blockIdx.x * SEQ;
    const int t = threadIdx.x;

    float4 x0 = *(const float4*)&p[t * 4];
    float4 x1 = *(const float4*)&p[1024 + t * 4];

    float mx = fmaxf(fmaxf(fmaxf(x0.x, x0.y), fmaxf(x0.z, x0.w)),
                     fmaxf(fmaxf(x1.x, x1.y), fmaxf(x1.z, x1.w)));
#pragma unroll
    for (int o = 32; o; o >>= 1) mx = fmaxf(mx, __shfl_xor(mx, o));

    __shared__ float red[8];
    if ((t & 63) == 0) red[t >> 6] = mx;
    __syncthreads();
    mx = fmaxf(fmaxf(red[0], red[1]), fmaxf(red[2], red[3]));

    x0.x = __expf(x0.x - mx); x0.y = __expf(x0.y - mx);
    x0.z = __expf(x0.z - mx); x0.w = __expf(x0.w - mx);
    x1.x = __expf(x1.x - mx); x1.y = __expf(x1.y - mx);
    x1.z = __expf(x1.z - mx); x1.w = __expf(x1.w - mx);

    float sm = (x0.x + x0.y + x0.z + x0.w) + (x1.x + x1.y + x1.z + x1.w);
#pragma unroll
    for (int o = 32; o; o >>= 1) sm += __shfl_xor(sm, o);
    if ((t & 63) == 0) red[4 + (t >> 6)] = sm;
    __syncthreads();
    sm = (red[4] + red[5]) + (red[6] + red[7]);

    const float inv = 1.0f / sm;
    x0.x *= inv; x0.y *= inv; x0.z *= inv; x0.w *= inv;
    x1.x *= inv; x1.y *= inv; x1.z *= inv; x1.w *= inv;
    *(float4*)&p[t * 4] = x0;
    *(float4*)&p[1024 + t * 4] = x1;
}

// ---------------------------------------------------------------------------
// kernel_launch
//   ws layout (floats):
//     q      : [0, 8388608)              -- [B,S,1024] fp32
//     v      : [8388608, 16777216)       -- [B,S,1024] fp32
//     scores : [16777216, 33554432)      -- [B,S,S]    fp32 (67 MB)
//   total 134.2 MB of workspace.
// ---------------------------------------------------------------------------
extern "C" void kernel_launch(void* const* d_in, const int* in_sizes, int n_in,
                              void* d_out, int out_size, void* d_ws, size_t ws_size,
                              hipStream_t stream)
{
    const float* query = (const float*)d_in[0];
    const float* value = (const float*)d_in[1];
    const float* Wq    = (const float*)d_in[2];
    const float* bq    = (const float*)d_in[3];
    const float* Wv    = (const float*)d_in[4];
    const float* bv    = (const float*)d_in[5];
    float* out = (float*)d_out;

    float* ws = (float*)d_ws;
    float* q  = ws;                      // 8192x1024
    float* v  = ws + (long)MTOT * H;     // 8192x1024
    float* sc = ws + 2L * MTOT * H;      // 4 x 2048 x 2048

    // --- projections: [8192,1024] @ [1024,1024] + bias ---
    {
        dim3 g(H / 128, MTOT / 128, 1);
        gemm_f32<false, true><<<g, 256, 0, stream>>>(
            query, Wq, bq, q, MTOT, H, H, 0, 0, 0);
        gemm_f32<false, true><<<g, 256, 0, stream>>>(
            value, Wv, bv, v, MTOT, H, H, 0, 0, 0);
    }

    // --- scores: per batch, [2048,1024] @ [2048,1024]^T -> [2048,2048] ---
    {
        dim3 g(SEQ / 128, SEQ / 128, NB);
        gemm_f32<true, false><<<g, 256, 0, stream>>>(
            q, v, nullptr, sc, SEQ, SEQ, H,
            (long)SEQ * H, (long)SEQ * H, (long)SEQ * SEQ);
    }

    // --- softmax over last axis, in place ---
    softmax_rows<<<NB * SEQ, 256, 0, stream>>>(sc);

    // --- context: per batch, [2048,2048] @ [2048,1024] -> [2048,1024] ---
    {
        dim3 g(H / 128, SEQ / 128, NB);
        gemm_f32<false, false><<<g, 256, 0, stream>>>(
            sc, v, nullptr, out, SEQ, H, SEQ,
            (long)SEQ * SEQ, (long)SEQ * H, (long)SEQ * H);
    }
}

// Round 2
// 462.806 us; speedup vs baseline: 2.8744x; 2.8744x over previous
//
#include <hip/hip_runtime.h>
#include <hip/hip_bf16.h>

// Problem: B=4, S=2048, HIDDEN=ATTN=1024.
// q = query@Wq + bq ; v = value@Wv + bv ; sc = q@v^T ; p = softmax(sc) ; out = p@v
// All GEMMs run as bf16 hi/lo-split MFMA (no fp32 MFMA on CDNA4).

typedef unsigned short u16;
typedef __attribute__((ext_vector_type(8))) short bf16x8;  // 4 VGPRs
typedef __attribute__((ext_vector_type(4))) float f32x4;

typedef __attribute__((address_space(1))) void gvoid_t;
typedef __attribute__((address_space(3))) void svoid_t;

// async global->LDS, 16B per lane, dest = wave-uniform base + lane*16
__device__ __forceinline__ void gll16(const void* g, void* l) {
    __builtin_amdgcn_global_load_lds((gvoid_t*)g, (svoid_t*)l, 16, 0, 0);
}

// bf16 round-to-nearest-even, manual (finite values only)
__device__ __forceinline__ u16 bf16rn(float x) {
    unsigned u = __float_as_uint(x);
    unsigned r = (u + 0x7FFFu + ((u >> 16) & 1u)) >> 16;
    return (u16)r;
}
__device__ __forceinline__ float bf2f(u16 h) {
    return __uint_as_float(((unsigned)h) << 16);
}

// ---------------------------------------------------------------------------
// MFMA GEMM, NT form: C[M,N] = sum_k A[m][k] * B[n][k]  (A,B row-major, K contig)
// SPLITA: A has hi+lo planes -> 3 products (ah*bh + ah*bl + al*bh)
// else  : single A plane     -> 2 products (a*bh + a*bl)
// OUTF32: write fp32 C (+bias) ; else write bf16 hi/lo planes (+bias)
// 128x128 tile, BK=32, 256 thr = 4 waves (2x2), 4x4 frags of 16x16x32 per wave.
// ---------------------------------------------------------------------------
template<bool SPLITA, bool BIAS, bool OUTF32>
__global__ __launch_bounds__(256)
void gemm_mfma(const u16* __restrict__ Ah, const u16* __restrict__ Al,
               const u16* __restrict__ Bh, const u16* __restrict__ Bl,
               const float* __restrict__ bias,
               float* __restrict__ Of, u16* __restrict__ Ohi, u16* __restrict__ Olo,
               int M, int N, int K, long sA, long sB, long sC)
{
    __shared__ __align__(16) u16 sm[SPLITA ? 16384 : 12288];
    u16* Ash = sm;                                   // [128][32]
    u16* Asl = SPLITA ? sm + 4096 : (u16*)nullptr;
    u16* Bsh = sm + (SPLITA ? 8192 : 4096);
    u16* Bsl = sm + (SPLITA ? 12288 : 8192);

    const long zb = blockIdx.z;
    Ah += zb * sA; if (SPLITA) Al += zb * sA;
    Bh += zb * sB; Bl += zb * sB;

    const int t = threadIdx.x, lane = t & 63, wv = t >> 6;
    const int wr = wv >> 1, wc = wv & 1;
    const int m0 = blockIdx.y << 7, n0 = blockIdx.x << 7;

    // staging: per tile 8KB = 8 wave-instrs; this wave issues u=0,1
    const int srow = (wv << 1) * 16 + (lane >> 2);   // u=1 adds 16 rows
    const int scol = (lane & 3) << 4;                // byte in 64B row

    const char* pAh0 = (const char*)(Ah + (long)(m0 + srow) * K) + scol;
    const char* pAh1 = pAh0 + (long)16 * K * 2;
    const char* pAl0 = SPLITA ? (const char*)(Al + (long)(m0 + srow) * K) + scol : nullptr;
    const char* pAl1 = SPLITA ? pAl0 + (long)16 * K * 2 : nullptr;
    const char* pBh0 = (const char*)(Bh + (long)(n0 + srow) * K) + scol;
    const char* pBh1 = pBh0 + (long)16 * K * 2;
    const char* pBl0 = (const char*)(Bl + (long)(n0 + srow) * K) + scol;
    const char* pBl1 = pBl0 + (long)16 * K * 2;

    u16* lAh0 = Ash + wv * 1024; u16* lAh1 = lAh0 + 512;
    u16* lAl0 = SPLITA ? Asl + wv * 1024 : (u16*)nullptr;
    u16* lAl1 = SPLITA ? lAl0 + 512 : (u16*)nullptr;
    u16* lBh0 = Bsh + wv * 1024; u16* lBh1 = lBh0 + 512;
    u16* lBl0 = Bsl + wv * 1024; u16* lBl1 = lBl0 + 512;

    // fragment LDS offsets (u16 units): row*32 + (lane>>4)*8
    const int afo = (wr * 64 + (lane & 15)) * 32 + (lane >> 4) * 8;
    const int bfo = (wc * 64 + (lane & 15)) * 32 + (lane >> 4) * 8;

    f32x4 acc[4][4];
#pragma unroll
    for (int i = 0; i < 4; ++i)
#pragma unroll
        for (int j = 0; j < 4; ++j) acc[i][j] = (f32x4)0.f;

    for (int k0 = 0; k0 < K; k0 += 32) {
        gll16(pAh0, lAh0); gll16(pAh1, lAh1);
        if (SPLITA) { gll16(pAl0, lAl0); gll16(pAl1, lAl1); }
        gll16(pBh0, lBh0); gll16(pBh1, lBh1);
        gll16(pBl0, lBl0); gll16(pBl1, lBl1);
        pAh0 += 64; pAh1 += 64; pBh0 += 64; pBh1 += 64; pBl0 += 64; pBl1 += 64;
        if (SPLITA) { pAl0 += 64; pAl1 += 64; }
        __syncthreads();

        bf16x8 ah[4], bh[4], bl[4];
#pragma unroll
        for (int i = 0; i < 4; ++i) {
            ah[i] = *(const bf16x8*)(Ash + afo + i * 512);
            bh[i] = *(const bf16x8*)(Bsh + bfo + i * 512);
            bl[i] = *(const bf16x8*)(Bsl + bfo + i * 512);
        }
#pragma unroll
        for (int i = 0; i < 4; ++i)
#pragma unroll
            for (int j = 0; j < 4; ++j)
                acc[i][j] = __builtin_amdgcn_mfma_f32_16x16x32_bf16(ah[i], bh[j], acc[i][j], 0, 0, 0);
#pragma unroll
        for (int i = 0; i < 4; ++i)
#pragma unroll
            for (int j = 0; j < 4; ++j)
                acc[i][j] = __builtin_amdgcn_mfma_f32_16x16x32_bf16(ah[i], bl[j], acc[i][j], 0, 0, 0);
        if (SPLITA) {
            bf16x8 al[4];
#pragma unroll
            for (int i = 0; i < 4; ++i) al[i] = *(const bf16x8*)(Asl + afo + i * 512);
#pragma unroll
            for (int i = 0; i < 4; ++i)
#pragma unroll
                for (int j = 0; j < 4; ++j)
                    acc[i][j] = __builtin_amdgcn_mfma_f32_16x16x32_bf16(al[i], bh[j], acc[i][j], 0, 0, 0);
        }
        __syncthreads();
    }

    // epilogue: C[row][col], col = lane&15 (+frag), row = (lane>>4)*4 + reg
    float bcol[4] = {0, 0, 0, 0};
    if (BIAS) {
#pragma unroll
        for (int j = 0; j < 4; ++j)
            bcol[j] = bias[n0 + wc * 64 + j * 16 + (lane & 15)];
    }
#pragma unroll
    for (int i = 0; i < 4; ++i) {
#pragma unroll
        for (int j = 0; j < 4; ++j) {
            const int col = n0 + wc * 64 + j * 16 + (lane & 15);
            const int row0 = m0 + wr * 64 + i * 16 + ((lane >> 4) << 2);
#pragma unroll
            for (int r = 0; r < 4; ++r) {
                float x = acc[i][j][r] + bcol[j];
                long o = zb * sC + (long)(row0 + r) * N + col;
                if (OUTF32) {
                    Of[o] = x;
                } else {
                    u16 h = bf16rn(x);
                    Ohi[o] = h;
                    Olo[o] = bf16rn(x - bf2f(h));
                }
            }
        }
    }
}

// ---------------------------------------------------------------------------
// fp32 -> bf16 hi/lo split, elementwise, 4 elems/thread
// ---------------------------------------------------------------------------
__global__ __launch_bounds__(256)
void split_f32(const float* __restrict__ in, u16* __restrict__ hi, u16* __restrict__ lo)
{
    long i = ((long)blockIdx.x * 256 + threadIdx.x) * 4;
    float4 v = *(const float4*)(in + i);
    ushort4 h, l;
    h.x = bf16rn(v.x); l.x = bf16rn(v.x - bf2f(h.x));
    h.y = bf16rn(v.y); l.y = bf16rn(v.y - bf2f(h.y));
    h.z = bf16rn(v.z); l.z = bf16rn(v.z - bf2f(h.z));
    h.w = bf16rn(v.w); l.w = bf16rn(v.w - bf2f(h.w));
    *(ushort4*)(hi + i) = h;
    *(ushort4*)(lo + i) = l;
}

// ---------------------------------------------------------------------------
// W [1024(k)][1024(n)] fp32 -> W^T [n][k] bf16 hi/lo (transpose + split)
// ---------------------------------------------------------------------------
__global__ __launch_bounds__(256)
void tsplit_w(const float* __restrict__ W, u16* __restrict__ hi, u16* __restrict__ lo)
{
    __shared__ float tile[32][33];
    const int n0v = blockIdx.x * 32, k0 = blockIdx.y * 32;
    const int r = threadIdx.x >> 5, c = threadIdx.x & 31;
#pragma unroll
    for (int it = 0; it < 4; ++it)
        tile[r + it * 8][c] = W[(long)(k0 + r + it * 8) * 1024 + n0v + c];
    __syncthreads();
#pragma unroll
    for (int it = 0; it < 4; ++it) {
        const int rr = r + it * 8;
        float x = tile[c][rr];                       // = W[k0+c][n0v+rr]
        u16 h = bf16rn(x);
        long o = (long)(n0v + rr) * 1024 + k0 + c;
        hi[o] = h;
        lo[o] = bf16rn(x - bf2f(h));
    }
}

// ---------------------------------------------------------------------------
// bf16 transpose per batch: src [4][2048(s)][1024(d)] -> dst [4][1024(d)][2048(s)]
// ---------------------------------------------------------------------------
__global__ __launch_bounds__(256)
void tr_bf16(const u16* __restrict__ src, u16* __restrict__ dst)
{
    __shared__ u16 tile[32][33];
    src += (long)blockIdx.z * 2048 * 1024;
    dst += (long)blockIdx.z * 1024 * 2048;
    const int s0 = blockIdx.x * 32, d0 = blockIdx.y * 32;
    const int r = threadIdx.x >> 5, c = threadIdx.x & 31;
#pragma unroll
    for (int it = 0; it < 4; ++it)
        tile[r + it * 8][c] = src[(long)(s0 + r + it * 8) * 1024 + d0 + c];
    __syncthreads();
#pragma unroll
    for (int it = 0; it < 4; ++it) {
        const int rr = r + it * 8;
        dst[(long)(d0 + rr) * 2048 + s0 + c] = tile[c][rr];
    }
}

// ---------------------------------------------------------------------------
// row softmax: fp32 scores [8192][2048] -> bf16 probs
// ---------------------------------------------------------------------------
__global__ __launch_bounds__(256)
void softmax_p(const float* __restrict__ S, u16* __restrict__ P)
{
    const float* p = S + (long)blockIdx.x * 2048;
    u16* o = P + (long)blockIdx.x * 2048;
    const int t = threadIdx.x;

    float4 x0 = *(const float4*)&p[t * 4];
    float4 x1 = *(const float4*)&p[1024 + t * 4];

    float mx = fmaxf(fmaxf(fmaxf(x0.x, x0.y), fmaxf(x0.z, x0.w)),
                     fmaxf(fmaxf(x1.x, x1.y), fmaxf(x1.z, x1.w)));
#pragma unroll
    for (int off = 32; off; off >>= 1) mx = fmaxf(mx, __shfl_xor(mx, off));

    __shared__ float red[8];
    if ((t & 63) == 0) red[t >> 6] = mx;
    __syncthreads();
    mx = fmaxf(fmaxf(red[0], red[1]), fmaxf(red[2], red[3]));

    x0.x = __expf(x0.x - mx); x0.y = __expf(x0.y - mx);
    x0.z = __expf(x0.z - mx); x0.w = __expf(x0.w - mx);
    x1.x = __expf(x1.x - mx); x1.y = __expf(x1.y - mx);
    x1.z = __expf(x1.z - mx); x1.w = __expf(x1.w - mx);

    float sm2 = (x0.x + x0.y + x0.z + x0.w) + (x1.x + x1.y + x1.z + x1.w);
#pragma unroll
    for (int off = 32; off; off >>= 1) sm2 += __shfl_xor(sm2, off);
    if ((t & 63) == 0) red[4 + (t >> 6)] = sm2;
    __syncthreads();
    sm2 = (red[4] + red[5]) + (red[6] + red[7]);

    const float inv = 1.0f / sm2;
    ushort4 y;
    y.x = bf16rn(x0.x * inv); y.y = bf16rn(x0.y * inv);
    y.z = bf16rn(x0.z * inv); y.w = bf16rn(x0.w * inv);
    *(ushort4*)(o + t * 4) = y;
    y.x = bf16rn(x1.x * inv); y.y = bf16rn(x1.y * inv);
    y.z = bf16rn(x1.z * inv); y.w = bf16rn(x1.w * inv);
    *(ushort4*)(o + 1024 + t * 4) = y;
}

// ---------------------------------------------------------------------------
// ws layout (bytes):
//   [0, 64M)        qx_hi,qx_lo,vx_hi,vx_lo (16M each bf16)  -> later sc fp32 (64M)
//   [64M, 96M)      q_hi,q_lo (16M each)                     -> later p bf16 (32M)
//   [96M, 128M)     v_hi,v_lo
//   [128M, 160M)    vT_hi,vT_lo
//   [160M, 168M)    WqT_hi,WqT_lo,WvT_hi,WvT_lo (2M each)
// total 168 MB
// ---------------------------------------------------------------------------
extern "C" void kernel_launch(void* const* d_in, const int* in_sizes, int n_in,
                              void* d_out, int out_size, void* d_ws, size_t ws_size,
                              hipStream_t stream)
{
    const float* query = (const float*)d_in[0];
    const float* value = (const float*)d_in[1];
    const float* Wq    = (const float*)d_in[2];
    const float* bq    = (const float*)d_in[3];
    const float* Wv    = (const float*)d_in[4];
    const float* bv    = (const float*)d_in[5];
    float* out = (float*)d_out;

    char* W = (char*)d_ws;
    u16* qx_hi = (u16*)(W);
    u16* qx_lo = qx_hi + 8388608;
    u16* vx_hi = qx_lo + 8388608;
    u16* vx_lo = vx_hi + 8388608;
    float* sc  = (float*)W;                       // overlaps qx/vx (dead by then)
    u16* q_hi  = (u16*)(W + 67108864);
    u16* q_lo  = q_hi + 8388608;
    u16* p     = (u16*)(W + 67108864);            // overlaps q_hi/q_lo (dead by then)
    u16* v_hi  = (u16*)(W + 100663296);
    u16* v_lo  = v_hi + 8388608;
    u16* vT_hi = (u16*)(W + 134217728);
    u16* vT_lo = vT_hi + 8388608;
    u16* WqT_hi = (u16*)(W + 167772160);
    u16* WqT_lo = WqT_hi + 1048576;
    u16* WvT_hi = WqT_lo + 1048576;
    u16* WvT_lo = WvT_hi + 1048576;

    // input splits
    split_f32<<<8192, 256, 0, stream>>>(query, qx_hi, qx_lo);
    split_f32<<<8192, 256, 0, stream>>>(value, vx_hi, vx_lo);
    tsplit_w<<<dim3(32, 32), 256, 0, stream>>>(Wq, WqT_hi, WqT_lo);
    tsplit_w<<<dim3(32, 32), 256, 0, stream>>>(Wv, WvT_hi, WvT_lo);

    // projections: [8192,1024] x [1024,1024]^T(+b) -> bf16 hi/lo
    gemm_mfma<true, true, false><<<dim3(8, 64, 1), 256, 0, stream>>>(
        qx_hi, qx_lo, WqT_hi, WqT_lo, bq, nullptr, q_hi, q_lo,
        8192, 1024, 1024, 0, 0, 0);
    gemm_mfma<true, true, false><<<dim3(8, 64, 1), 256, 0, stream>>>(
        vx_hi, vx_lo, WvT_hi, WvT_lo, bv, nullptr, v_hi, v_lo,
        8192, 1024, 1024, 0, 0, 0);

    // v^T for the PV GEMM
    tr_bf16<<<dim3(64, 32, 4), 256, 0, stream>>>(v_hi, vT_hi);
    tr_bf16<<<dim3(64, 32, 4), 256, 0, stream>>>(v_lo, vT_lo);

    // scores: per batch [2048,1024] x [2048,1024]^T -> fp32
    gemm_mfma<true, false, true><<<dim3(16, 16, 4), 256, 0, stream>>>(
        q_hi, q_lo, v_hi, v_lo, nullptr, sc, nullptr, nullptr,
        2048, 2048, 1024, 2048L * 1024, 2048L * 1024, 2048L * 2048);

    softmax_p<<<8192, 256, 0, stream>>>(sc, p);

    // context: per batch [2048,2048] x [1024,2048]^T -> fp32 out
    gemm_mfma<false, false, true><<<dim3(8, 16, 4), 256, 0, stream>>>(
        p, nullptr, vT_hi, vT_lo, nullptr, out, nullptr, nullptr,
        2048, 1024, 2048, 2048L * 2048, 1024L * 2048, 2048L * 1024);
}

// Round 3
// 441.668 us; speedup vs baseline: 3.0120x; 1.0479x over previous
//
#include <hip/hip_runtime.h>
#include <hip/hip_bf16.h>

// Problem: B=4, S=2048, HIDDEN=ATTN=1024.
// q = query@Wq + bq ; v = value@Wv + bv ; sc = q@v^T ; p = softmax(sc) ; out = p@v
// GEMMs as bf16 hi/lo-split MFMA. proj+scores use a 256^2-tile 8-phase
// pipelined kernel (T2 swizzle + T3/T4 counted vmcnt + T5 setprio); hi/lo
// 3-term products are folded in as an extended K (3 planes x 1024).

typedef unsigned short u16;
typedef __attribute__((ext_vector_type(8))) short bf16x8;  // 4 VGPRs
typedef __attribute__((ext_vector_type(4))) float f32x4;

typedef __attribute__((address_space(1))) void gvoid_t;
typedef __attribute__((address_space(3))) void svoid_t;

__device__ __forceinline__ void gll16(const void* g, void* l) {
    __builtin_amdgcn_global_load_lds((gvoid_t*)g, (svoid_t*)l, 16, 0, 0);
}

__device__ __forceinline__ u16 bf16rn(float x) {
    unsigned u = __float_as_uint(x);
    unsigned r = (u + 0x7FFFu + ((u >> 16) & 1u)) >> 16;
    return (u16)r;
}
__device__ __forceinline__ float bf2f(u16 h) {
    return __uint_as_float(((unsigned)h) << 16);
}

__device__ __forceinline__ const char* sel3(const char* p0, const char* p1,
                                            const char* p2, int i) {
    return i == 0 ? p0 : (i == 1 ? p1 : p2);
}

// ===========================================================================
// 8-phase 256x256 NT GEMM, BK=64, 512 thr = 8 waves (2M x 4N), LDS 128 KiB
// (2 bufs x {A:2 halves, B:2 halves} x 16 KiB). K' = 48 steps = 3 planes of
// 1024 elements (plane row stride fixed 2048 B).
//   C[m][n] = sum_planes sum_k Aplane[m][k] * Bplane[n][k]
// A-half mh = M-rows with bit6==mh (local row = wm*64 + ...), B-half nh =
// N-rows with bit5==nh. LDS swizzle: slot (row, c) holds global (row,
// c ^ ((row&7)<<4)); staging pre-swizzles the GLOBAL source (rule 21).
// Per K-step: 4 phases = C-quadrants (mh,nh); phase stages one half-tile:
//   ph0:(0,0)+A1(s+1)  ph1:(0,1)+B1(s+1)  ph2:(1,0)+A0(s+2)  ph3:(1,1)+B0(s+2)
// vmcnt(4) once per step (2 half-tiles = 4 loads stay in flight).
// ===========================================================================
#define NSK 48

#define STAGE_A(T, mh) {                                                      \
    const char* _p = sel3(A0z, A1z, A2z, (T) >> 4) + (long)((T) & 15) * 128;  \
    char* _d = smem + (((T) & 1) << 16) + ((mh) << 14) + (w << 10);           \
    gll16(_p + offA##mh##0, _d);                                              \
    gll16(_p + offA##mh##1, _d + 8192); }

#define STAGE_B(T, nh) {                                                      \
    const char* _p = sel3(B0z, B1z, B2z, (T) >> 4) + (long)((T) & 15) * 128;  \
    char* _d = smem + (((T) & 1) << 16) + 32768 + ((nh) << 14) + (w << 10);   \
    gll16(_p + offB##nh##0, _d);                                              \
    gll16(_p + offB##nh##1, _d + 8192); }

#define VM4 { asm volatile("s_waitcnt vmcnt(4)" ::: "memory");                \
              __builtin_amdgcn_sched_barrier(0); }
#define VM0 { asm volatile("s_waitcnt vmcnt(0)" ::: "memory");                \
              __builtin_amdgcn_sched_barrier(0); }

#define PHASE(mh, nh, STAGE, ENDW)                                            \
  {                                                                           \
    if ((nh) == 0) {                                                          \
      _Pragma("unroll") for (int mi = 0; mi < 4; ++mi)                        \
        _Pragma("unroll") for (int ks = 0; ks < 2; ++ks)                      \
          afr[mi][ks] = *(const bf16x8*)(smem + bufb + ((mh) << 14) +         \
              aRdB + mi * 2048 + csw[ks]);                                    \
    }                                                                         \
    bf16x8 bfr[2][2];                                                         \
    _Pragma("unroll") for (int ni = 0; ni < 2; ++ni)                          \
      _Pragma("unroll") for (int ks = 0; ks < 2; ++ks)                        \
        bfr[ni][ks] = *(const bf16x8*)(smem + bufb + ((nh) << 14) +           \
            bRdB + ni * 2048 + csw[ks]);                                      \
    STAGE;                                                                    \
    __builtin_amdgcn_s_barrier();                                             \
    asm volatile("s_waitcnt lgkmcnt(0)" ::: "memory");                        \
    __builtin_amdgcn_sched_barrier(0);                                        \
    __builtin_amdgcn_s_setprio(1);                                            \
    _Pragma("unroll") for (int mi = 0; mi < 4; ++mi)                          \
      _Pragma("unroll") for (int ni = 0; ni < 2; ++ni)                        \
        _Pragma("unroll") for (int ks = 0; ks < 2; ++ks)                      \
          acc[(mh) * 4 + mi][(nh) * 2 + ni] =                                 \
              __builtin_amdgcn_mfma_f32_16x16x32_bf16(                        \
                  afr[mi][ks], bfr[ni][ks],                                   \
                  acc[(mh) * 4 + mi][(nh) * 2 + ni], 0, 0, 0);                \
    __builtin_amdgcn_s_setprio(0);                                            \
    ENDW;                                                                     \
    __builtin_amdgcn_s_barrier();                                             \
  }

template<bool OUTF32>
__global__ __launch_bounds__(512, 2)
void gemm8(const char* a0, const char* a1, const char* a2, long zA,
           const char* b0, const char* b1, const char* b2, long zB,
           float* __restrict__ Of, u16* __restrict__ Ohi, u16* __restrict__ Olo,
           long zC, const float* __restrict__ bias0,
           const float* __restrict__ bias1, int N)
{
    extern __shared__ char smem[];
    const int t = threadIdx.x, lane = t & 63, w = t >> 6;
    const int wm = w >> 2, wn = w & 3;
    const int n0 = blockIdx.x << 8, m0 = blockIdx.y << 8;
    const int z = blockIdx.z;

    const char* A0z = a0 + (long)z * zA;
    const char* A1z = a1 + (long)z * zA;
    const char* A2z = a2 + (long)z * zA;
    const char* B0z = b0 + (long)z * zB;
    const char* B1z = b1 + (long)z * zB;
    const char* B2z = b2 + (long)z * zB;

    // ---- staging geometry (per thread): LDS linear (lr, c) <- global
    // (grow, c ^ ((lr&7)<<4)); lr = t>>3 (+64 for u=1), c = (t&7)*16.
    const int lr0 = t >> 3;                                   // 0..63
    const long cg = (long)((((t & 7) ^ ((t >> 3) & 7)) << 4));
    const long offA00 = (long)(m0 + lr0) * 2048 + cg;             // A half0,u0
    const long offA01 = offA00 + 128L * 2048;                     // u1 (+128 rows)
    const long offA10 = (long)(m0 + 64 + lr0) * 2048 + cg;        // A half1
    const long offA11 = offA10 + 128L * 2048;
    const long offB00 = (long)(n0 + ((lr0 >> 5) << 6) + (lr0 & 31)) * 2048 + cg;
    const long offB01 = offB00 + 128L * 2048;
    const long offB10 = offB00 + 32L * 2048;                      // nh=1: +32 rows
    const long offB11 = offB10 + 128L * 2048;

    // ---- fragment-read geometry: row lr -> byte lr*128 + (c ^ ((lane&7)<<4))
    const int swl = (lane & 7) << 4;
    const int csw[2] = { (((lane >> 4) << 4)) ^ swl,
                         (((lane >> 4) << 4) + 64) ^ swl };
    const int aRdB = (wm * 64 + (lane & 15)) * 128;
    const int bRdB = 32768 + (wn * 32 + (lane & 15)) * 128;

    f32x4 acc[8][4];
#pragma unroll
    for (int i = 0; i < 8; ++i)
#pragma unroll
        for (int j = 0; j < 4; ++j) acc[i][j] = (f32x4)0.f;
    bf16x8 afr[4][2];

    // ---- prologue: tile0 (4 half-tiles) + tile1 A0,B0; wait tile0 ----
    STAGE_A(0, 0); STAGE_B(0, 0); STAGE_A(0, 1); STAGE_B(0, 1);
    STAGE_A(1, 0); STAGE_B(1, 0);
    asm volatile("s_waitcnt vmcnt(4)" ::: "memory");
    __builtin_amdgcn_sched_barrier(0);
    __builtin_amdgcn_s_barrier();

    // ---- steady loop ----
    for (int s = 0; s < NSK - 2; ++s) {
        const int bufb = (s & 1) << 16;
        PHASE(0, 0, STAGE_A(s + 1, 1), );
        PHASE(0, 1, STAGE_B(s + 1, 1), );
        PHASE(1, 0, STAGE_A(s + 2, 0), );
        PHASE(1, 1, STAGE_B(s + 2, 0), VM4);
    }
    {   // s = NSK-2 (even): stage only A1/B1 of last tile; drain fully
        const int bufb = ((NSK - 2) & 1) << 16;
        PHASE(0, 0, STAGE_A(NSK - 1, 1), );
        PHASE(0, 1, STAGE_B(NSK - 1, 1), );
        PHASE(1, 0, , );
        PHASE(1, 1, , VM0);
    }
    {   // s = NSK-1: compute only
        const int bufb = ((NSK - 1) & 1) << 16;
        PHASE(0, 0, , );
        PHASE(0, 1, , );
        PHASE(1, 0, , );
        PHASE(1, 1, , );
    }

    // ---- epilogue: C[row][col], col = lane&15, row = (lane>>4)*4 + r ----
    const int r0 = m0 + wm * 128 + ((lane >> 4) << 2);
    const int c0 = n0 + wn * 64 + (lane & 15);
    if (OUTF32) {
        float* Co = Of + (long)z * zC;
#pragma unroll
        for (int mi = 0; mi < 8; ++mi)
#pragma unroll
            for (int nj = 0; nj < 4; ++nj)
#pragma unroll
                for (int r = 0; r < 4; ++r)
                    Co[(long)(r0 + mi * 16 + r) * N + c0 + nj * 16] =
                        acc[mi][nj][r];
    } else {
        const float* bs = z ? bias1 : bias0;
        float bc[4];
#pragma unroll
        for (int nj = 0; nj < 4; ++nj) bc[nj] = bs[c0 + nj * 16];
        u16* Oh = Ohi + (long)z * zC;
        u16* Ol = Olo + (long)z * zC;
#pragma unroll
        for (int mi = 0; mi < 8; ++mi)
#pragma unroll
            for (int nj = 0; nj < 4; ++nj)
#pragma unroll
                for (int r = 0; r < 4; ++r) {
                    float x = acc[mi][nj][r] + bc[nj];
                    long o = (long)(r0 + mi * 16 + r) * N + c0 + nj * 16;
                    u16 h = bf16rn(x);
                    Oh[o] = h;
                    Ol[o] = bf16rn(x - bf2f(h));
                }
    }
}

// ---------------------------------------------------------------------------
// PV GEMM (proven R2 kernel): C = A @ B^T, A single bf16 plane (probs),
// B hi+lo planes -> 2 products. 128x128 tile, BK=32, 4 waves.
// ---------------------------------------------------------------------------
__global__ __launch_bounds__(256)
void gemm_pv(const u16* __restrict__ Ah, const u16* __restrict__ Bh,
             const u16* __restrict__ Bl, float* __restrict__ Of,
             int N, int K, long sA, long sB, long sC)
{
    __shared__ __align__(16) u16 sm[12288];
    u16* Ash = sm;
    u16* Bsh = sm + 4096;
    u16* Bsl = sm + 8192;

    const long zb = blockIdx.z;
    Ah += zb * sA; Bh += zb * sB; Bl += zb * sB;

    const int t = threadIdx.x, lane = t & 63, wv = t >> 6;
    const int wr = wv >> 1, wc = wv & 1;
    const int m0 = blockIdx.y << 7, n0 = blockIdx.x << 7;

    const int srow = (wv << 1) * 16 + (lane >> 2);
    const int scol = (lane & 3) << 4;

    const char* pAh0 = (const char*)(Ah + (long)(m0 + srow) * K) + scol;
    const char* pAh1 = pAh0 + (long)16 * K * 2;
    const char* pBh0 = (const char*)(Bh + (long)(n0 + srow) * K) + scol;
    const char* pBh1 = pBh0 + (long)16 * K * 2;
    const char* pBl0 = (const char*)(Bl + (long)(n0 + srow) * K) + scol;
    const char* pBl1 = pBl0 + (long)16 * K * 2;

    u16* lAh0 = Ash + wv * 1024; u16* lAh1 = lAh0 + 512;
    u16* lBh0 = Bsh + wv * 1024; u16* lBh1 = lBh0 + 512;
    u16* lBl0 = Bsl + wv * 1024; u16* lBl1 = lBl0 + 512;

    const int afo = (wr * 64 + (lane & 15)) * 32 + (lane >> 4) * 8;
    const int bfo = (wc * 64 + (lane & 15)) * 32 + (lane >> 4) * 8;

    f32x4 acc[4][4];
#pragma unroll
    for (int i = 0; i < 4; ++i)
#pragma unroll
        for (int j = 0; j < 4; ++j) acc[i][j] = (f32x4)0.f;

    for (int k0 = 0; k0 < K; k0 += 32) {
        gll16(pAh0, lAh0); gll16(pAh1, lAh1);
        gll16(pBh0, lBh0); gll16(pBh1, lBh1);
        gll16(pBl0, lBl0); gll16(pBl1, lBl1);
        pAh0 += 64; pAh1 += 64; pBh0 += 64; pBh1 += 64; pBl0 += 64; pBl1 += 64;
        __syncthreads();

        bf16x8 ah[4], bh[4], bl[4];
#pragma unroll
        for (int i = 0; i < 4; ++i) {
            ah[i] = *(const bf16x8*)(Ash + afo + i * 512);
            bh[i] = *(const bf16x8*)(Bsh + bfo + i * 512);
            bl[i] = *(const bf16x8*)(Bsl + bfo + i * 512);
        }
#pragma unroll
        for (int i = 0; i < 4; ++i)
#pragma unroll
            for (int j = 0; j < 4; ++j)
                acc[i][j] = __builtin_amdgcn_mfma_f32_16x16x32_bf16(ah[i], bh[j], acc[i][j], 0, 0, 0);
#pragma unroll
        for (int i = 0; i < 4; ++i)
#pragma unroll
            for (int j = 0; j < 4; ++j)
                acc[i][j] = __builtin_amdgcn_mfma_f32_16x16x32_bf16(ah[i], bl[j], acc[i][j], 0, 0, 0);
        __syncthreads();
    }

#pragma unroll
    for (int i = 0; i < 4; ++i)
#pragma unroll
        for (int j = 0; j < 4; ++j) {
            const int col = n0 + wc * 64 + j * 16 + (lane & 15);
            const int row0 = m0 + wr * 64 + i * 16 + ((lane >> 4) << 2);
#pragma unroll
            for (int r = 0; r < 4; ++r)
                Of[zb * sC + (long)(row0 + r) * N + col] = acc[i][j][r];
        }
}

// ---------------------------------------------------------------------------
__global__ __launch_bounds__(256)
void split_f32(const float* __restrict__ in, u16* __restrict__ hi, u16* __restrict__ lo)
{
    long i = ((long)blockIdx.x * 256 + threadIdx.x) * 4;
    float4 v = *(const float4*)(in + i);
    ushort4 h, l;
    h.x = bf16rn(v.x); l.x = bf16rn(v.x - bf2f(h.x));
    h.y = bf16rn(v.y); l.y = bf16rn(v.y - bf2f(h.y));
    h.z = bf16rn(v.z); l.z = bf16rn(v.z - bf2f(h.z));
    h.w = bf16rn(v.w); l.w = bf16rn(v.w - bf2f(h.w));
    *(ushort4*)(hi + i) = h;
    *(ushort4*)(lo + i) = l;
}

__global__ __launch_bounds__(256)
void tsplit_w(const float* __restrict__ W, u16* __restrict__ hi, u16* __restrict__ lo)
{
    __shared__ float tile[32][33];
    const int n0v = blockIdx.x * 32, k0 = blockIdx.y * 32;
    const int r = threadIdx.x >> 5, c = threadIdx.x & 31;
#pragma unroll
    for (int it = 0; it < 4; ++it)
        tile[r + it * 8][c] = W[(long)(k0 + r + it * 8) * 1024 + n0v + c];
    __syncthreads();
#pragma unroll
    for (int it = 0; it < 4; ++it) {
        const int rr = r + it * 8;
        float x = tile[c][rr];
        u16 h = bf16rn(x);
        long o = (long)(n0v + rr) * 1024 + k0 + c;
        hi[o] = h;
        lo[o] = bf16rn(x - bf2f(h));
    }
}

__global__ __launch_bounds__(256)
void tr_bf16(const u16* __restrict__ src, u16* __restrict__ dst)
{
    __shared__ u16 tile[32][33];
    src += (long)blockIdx.z * 2048 * 1024;
    dst += (long)blockIdx.z * 1024 * 2048;
    const int s0 = blockIdx.x * 32, d0 = blockIdx.y * 32;
    const int r = threadIdx.x >> 5, c = threadIdx.x & 31;
#pragma unroll
    for (int it = 0; it < 4; ++it)
        tile[r + it * 8][c] = src[(long)(s0 + r + it * 8) * 1024 + d0 + c];
    __syncthreads();
#pragma unroll
    for (int it = 0; it < 4; ++it) {
        const int rr = r + it * 8;
        dst[(long)(d0 + rr) * 2048 + s0 + c] = tile[c][rr];
    }
}

__global__ __launch_bounds__(256)
void softmax_p(const float* __restrict__ S, u16* __restrict__ P)
{
    const float* p = S + (long)blockIdx.x * 2048;
    u16* o = P + (long)blockIdx.x * 2048;
    const int t = threadIdx.x;

    float4 x0 = *(const float4*)&p[t * 4];
    float4 x1 = *(const float4*)&p[1024 + t * 4];

    float mx = fmaxf(fmaxf(fmaxf(x0.x, x0.y), fmaxf(x0.z, x0.w)),
                     fmaxf(fmaxf(x1.x, x1.y), fmaxf(x1.z, x1.w)));
#pragma unroll
    for (int off = 32; off; off >>= 1) mx = fmaxf(mx, __shfl_xor(mx, off));

    __shared__ float red[8];
    if ((t & 63) == 0) red[t >> 6] = mx;
    __syncthreads();
    mx = fmaxf(fmaxf(red[0], red[1]), fmaxf(red[2], red[3]));

    x0.x = __expf(x0.x - mx); x0.y = __expf(x0.y - mx);
    x0.z = __expf(x0.z - mx); x0.w = __expf(x0.w - mx);
    x1.x = __expf(x1.x - mx); x1.y = __expf(x1.y - mx);
    x1.z = __expf(x1.z - mx); x1.w = __expf(x1.w - mx);

    float sm2 = (x0.x + x0.y + x0.z + x0.w) + (x1.x + x1.y + x1.z + x1.w);
#pragma unroll
    for (int off = 32; off; off >>= 1) sm2 += __shfl_xor(sm2, off);
    if ((t & 63) == 0) red[4 + (t >> 6)] = sm2;
    __syncthreads();
    sm2 = (red[4] + red[5]) + (red[6] + red[7]);

    const float inv = 1.0f / sm2;
    ushort4 y;
    y.x = bf16rn(x0.x * inv); y.y = bf16rn(x0.y * inv);
    y.z = bf16rn(x0.z * inv); y.w = bf16rn(x0.w * inv);
    *(ushort4*)(o + t * 4) = y;
    y.x = bf16rn(x1.x * inv); y.y = bf16rn(x1.y * inv);
    y.z = bf16rn(x1.z * inv); y.w = bf16rn(x1.w * inv);
    *(ushort4*)(o + 1024 + t * 4) = y;
}

// ---------------------------------------------------------------------------
// ws layout (MiB): [0,64) qx_hi,qx_lo,vx_hi,vx_lo (16 each) -> later sc fp32
// (exactly 64); [64,96) q_hi,q_lo -> later p bf16; [96,128) v_hi,v_lo;
// [128,160) vT_hi,vT_lo; [160,168) WqT_hi,WqT_lo,WvT_hi,WvT_lo (2 each).
// ---------------------------------------------------------------------------
extern "C" void kernel_launch(void* const* d_in, const int* in_sizes, int n_in,
                              void* d_out, int out_size, void* d_ws, size_t ws_size,
                              hipStream_t stream)
{
    const float* query = (const float*)d_in[0];
    const float* value = (const float*)d_in[1];
    const float* Wq    = (const float*)d_in[2];
    const float* bq    = (const float*)d_in[3];
    const float* Wv    = (const float*)d_in[4];
    const float* bv    = (const float*)d_in[5];
    float* out = (float*)d_out;

    char* W = (char*)d_ws;
    u16* qx_hi = (u16*)(W);
    u16* qx_lo = qx_hi + 8388608;
    u16* vx_hi = qx_lo + 8388608;
    u16* vx_lo = vx_hi + 8388608;
    float* sc  = (float*)W;                       // overlaps qx/vx (dead by then)
    u16* q_hi  = (u16*)(W + 67108864);
    u16* q_lo  = q_hi + 8388608;
    u16* p     = (u16*)(W + 67108864);            // overlaps q_hi/q_lo (dead by then)
    u16* v_hi  = (u16*)(W + 100663296);
    u16* v_lo  = v_hi + 8388608;
    u16* vT_hi = (u16*)(W + 134217728);
    u16* vT_lo = vT_hi + 8388608;
    u16* WqT_hi = (u16*)(W + 167772160);
    u16* WqT_lo = WqT_hi + 1048576;
    u16* WvT_hi = WqT_lo + 1048576;
    u16* WvT_lo = WvT_hi + 1048576;

    hipFuncSetAttribute((const void*)&gemm8<false>,
                        hipFuncAttributeMaxDynamicSharedMemorySize, 131072);
    hipFuncSetAttribute((const void*)&gemm8<true>,
                        hipFuncAttributeMaxDynamicSharedMemorySize, 131072);

    // input splits
    split_f32<<<8192, 256, 0, stream>>>(query, qx_hi, qx_lo);
    split_f32<<<8192, 256, 0, stream>>>(value, vx_hi, vx_lo);
    tsplit_w<<<dim3(32, 32), 256, 0, stream>>>(Wq, WqT_hi, WqT_lo);
    tsplit_w<<<dim3(32, 32), 256, 0, stream>>>(Wv, WvT_hi, WvT_lo);

    // fused projections (z=0: q, z=1: v): planes A=[x_hi,x_hi,x_lo],
    // B=[W_hi,W_lo,W_hi]; out bf16 hi/lo (+bias)
    gemm8<false><<<dim3(4, 32, 2), 512, 131072, stream>>>(
        (const char*)qx_hi, (const char*)qx_hi, (const char*)qx_lo, 33554432L,
        (const char*)WqT_hi, (const char*)WqT_lo, (const char*)WqT_hi, 4194304L,
        nullptr, q_hi, q_lo, 16777216L, bq, bv, 1024);

    // v^T for the PV GEMM
    tr_bf16<<<dim3(64, 32, 4), 256, 0, stream>>>(v_hi, vT_hi);
    tr_bf16<<<dim3(64, 32, 4), 256, 0, stream>>>(v_lo, vT_lo);

    // scores: per batch, planes A=[q_hi,q_hi,q_lo], B=[v_hi,v_lo,v_hi] -> fp32
    gemm8<true><<<dim3(8, 8, 4), 512, 131072, stream>>>(
        (const char*)q_hi, (const char*)q_hi, (const char*)q_lo, 4194304L,
        (const char*)v_hi, (const char*)v_lo, (const char*)v_hi, 4194304L,
        sc, nullptr, nullptr, 4194304L, nullptr, nullptr, 2048);

    softmax_p<<<8192, 256, 0, stream>>>(sc, p);

    // context: per batch [2048,2048] @ [1024,2048]^T -> fp32 out
    gemm_pv<<<dim3(8, 16, 4), 256, 0, stream>>>(
        p, vT_hi, vT_lo, out,
        1024, 2048, 2048L * 2048, 1024L * 2048, 2048L * 1024);
}

// Round 5
// 416.626 us; speedup vs baseline: 3.1930x; 1.0601x over previous
//
#include <hip/hip_runtime.h>
#include <hip/hip_bf16.h>

// Problem: B=4, S=2048, HIDDEN=ATTN=1024.
// q = query@Wq + bq ; v = value@Wv + bv ; sc = q@v^T ; p = softmax(sc) ; out = p@v
// All GEMMs bf16 hi/lo-split MFMA, 8-phase pipelined 256-wide-tile kernels
// (T2 swizzle + T3/T4 counted vmcnt + T5 setprio + T1 XCD-chunked grid).

typedef unsigned short u16;
typedef __attribute__((ext_vector_type(8))) short bf16x8;  // 4 VGPRs
typedef __attribute__((ext_vector_type(4))) float f32x4;

typedef __attribute__((address_space(1))) void gvoid_t;
typedef __attribute__((address_space(3))) void svoid_t;

__device__ __forceinline__ void gll16(const void* g, void* l) {
    __builtin_amdgcn_global_load_lds((gvoid_t*)g, (svoid_t*)l, 16, 0, 0);
}

__device__ __forceinline__ u16 bf16rn(float x) {
    unsigned u = __float_as_uint(x);
    unsigned r = (u + 0x7FFFu + ((u >> 16) & 1u)) >> 16;
    return (u16)r;
}
__device__ __forceinline__ float bf2f(u16 h) {
    return __uint_as_float(((unsigned)h) << 16);
}

__device__ __forceinline__ const char* sel3(const char* p0, const char* p1,
                                            const char* p2, int i) {
    return i == 0 ? p0 : (i == 1 ? p1 : p2);
}

// ===========================================================================
// 8-phase 256x256 NT GEMM, BK=64, 512 thr = 8 waves (2M x 4N), LDS 128 KiB.
// K' = 48 steps = 3 planes of 1024 (plane row stride fixed 2048 B).
// SCHEME: XCD-chunked flat-grid decode. 0: (x8,y8,z4)  1: (x4,y32,z2).
// ===========================================================================
#define NSK 48

#define STAGE_A(T, mh) {                                                      \
    const char* _p = sel3(A0z, A1z, A2z, (T) >> 4) + (long)((T) & 15) * 128;  \
    char* _d = smem + (((T) & 1) << 16) + ((mh) << 14) + (w << 10);           \
    gll16(_p + offA##mh##0, _d);                                              \
    gll16(_p + offA##mh##1, _d + 8192); }

#define STAGE_B(T, nh) {                                                      \
    const char* _p = sel3(B0z, B1z, B2z, (T) >> 4) + (long)((T) & 15) * 128;  \
    char* _d = smem + (((T) & 1) << 16) + 32768 + ((nh) << 14) + (w << 10);   \
    gll16(_p + offB##nh##0, _d);                                              \
    gll16(_p + offB##nh##1, _d + 8192); }

#define VM4 { asm volatile("s_waitcnt vmcnt(4)" ::: "memory");                \
              __builtin_amdgcn_sched_barrier(0); }
#define VM0 { asm volatile("s_waitcnt vmcnt(0)" ::: "memory");                \
              __builtin_amdgcn_sched_barrier(0); }

#define PHASE(mh, nh, STAGE, ENDW)                                            \
  {                                                                           \
    if ((nh) == 0) {                                                          \
      _Pragma("unroll") for (int mi = 0; mi < 4; ++mi)                        \
        _Pragma("unroll") for (int ks = 0; ks < 2; ++ks)                      \
          afr[mi][ks] = *(const bf16x8*)(smem + bufb + ((mh) << 14) +         \
              aRdB + mi * 2048 + csw[ks]);                                    \
    }                                                                         \
    bf16x8 bfr[2][2];                                                         \
    _Pragma("unroll") for (int ni = 0; ni < 2; ++ni)                          \
      _Pragma("unroll") for (int ks = 0; ks < 2; ++ks)                        \
        bfr[ni][ks] = *(const bf16x8*)(smem + bufb + ((nh) << 14) +           \
            bRdB + ni * 2048 + csw[ks]);                                      \
    STAGE;                                                                    \
    __builtin_amdgcn_s_barrier();                                             \
    asm volatile("s_waitcnt lgkmcnt(0)" ::: "memory");                        \
    __builtin_amdgcn_sched_barrier(0);                                        \
    __builtin_amdgcn_s_setprio(1);                                            \
    _Pragma("unroll") for (int mi = 0; mi < 4; ++mi)                          \
      _Pragma("unroll") for (int ni = 0; ni < 2; ++ni)                        \
        _Pragma("unroll") for (int ks = 0; ks < 2; ++ks)                      \
          acc[(mh) * 4 + mi][(nh) * 2 + ni] =                                 \
              __builtin_amdgcn_mfma_f32_16x16x32_bf16(                        \
                  afr[mi][ks], bfr[ni][ks],                                   \
                  acc[(mh) * 4 + mi][(nh) * 2 + ni], 0, 0, 0);                \
    __builtin_amdgcn_s_setprio(0);                                            \
    ENDW;                                                                     \
    __builtin_amdgcn_s_barrier();                                             \
  }

template<bool OUTF32, int SCHEME>
__global__ __launch_bounds__(512, 2)
void gemm8(const char* a0, const char* a1, const char* a2, long zA,
           const char* b0, const char* b1, const char* b2, long zB,
           float* __restrict__ Of, u16* __restrict__ Ohi, u16* __restrict__ Olo,
           long zC, const float* __restrict__ bias0,
           const float* __restrict__ bias1, int N)
{
    extern __shared__ char smem[];
    const int t = threadIdx.x, lane = t & 63, w = t >> 6;
    const int wm = w >> 2, wn = w & 3;

    // T1: XCD-chunked decode (bid%8 = XCD round-robin assumption; perf-only)
    const int bid = blockIdx.x;
    const int xcd = bid & 7, bi = bid >> 3;
    int m0, n0, z;
    if (SCHEME == 0) {            // scores: x=8 N-tiles, y=8 M-tiles, z=4
        z = xcd >> 1;
        m0 = (((xcd & 1) << 2) | (bi >> 3)) << 8;
        n0 = (bi & 7) << 8;
    } else {                      // proj: x=4, y=32, z=2
        m0 = ((xcd << 2) | (bi >> 3)) << 8;
        n0 = (bi & 3) << 8;
        z = (bi >> 2) & 1;
    }

    const char* A0z = a0 + (long)z * zA;
    const char* A1z = a1 + (long)z * zA;
    const char* A2z = a2 + (long)z * zA;
    const char* B0z = b0 + (long)z * zB;
    const char* B1z = b1 + (long)z * zB;
    const char* B2z = b2 + (long)z * zB;

    // staging: LDS linear (lr, c) <- global (grow, c ^ ((lr&7)<<4))
    const int lr0 = t >> 3;
    const long cg = (long)((((t & 7) ^ ((t >> 3) & 7)) << 4));
    const long offA00 = (long)(m0 + lr0) * 2048 + cg;
    const long offA01 = offA00 + 128L * 2048;
    const long offA10 = (long)(m0 + 64 + lr0) * 2048 + cg;
    const long offA11 = offA10 + 128L * 2048;
    const long offB00 = (long)(n0 + ((lr0 >> 5) << 6) + (lr0 & 31)) * 2048 + cg;
    const long offB01 = offB00 + 128L * 2048;
    const long offB10 = offB00 + 32L * 2048;
    const long offB11 = offB10 + 128L * 2048;

    const int swl = (lane & 7) << 4;
    const int csw[2] = { (((lane >> 4) << 4)) ^ swl,
                         (((lane >> 4) << 4) + 64) ^ swl };
    const int aRdB = (wm * 64 + (lane & 15)) * 128;
    const int bRdB = 32768 + (wn * 32 + (lane & 15)) * 128;

    f32x4 acc[8][4];
#pragma unroll
    for (int i = 0; i < 8; ++i)
#pragma unroll
        for (int j = 0; j < 4; ++j) acc[i][j] = (f32x4)0.f;
    bf16x8 afr[4][2];

    STAGE_A(0, 0); STAGE_B(0, 0); STAGE_A(0, 1); STAGE_B(0, 1);
    STAGE_A(1, 0); STAGE_B(1, 0);
    asm volatile("s_waitcnt vmcnt(4)" ::: "memory");
    __builtin_amdgcn_sched_barrier(0);
    __builtin_amdgcn_s_barrier();

    for (int s = 0; s < NSK - 2; ++s) {
        const int bufb = (s & 1) << 16;
        PHASE(0, 0, STAGE_A(s + 1, 1), );
        PHASE(0, 1, STAGE_B(s + 1, 1), );
        PHASE(1, 0, STAGE_A(s + 2, 0), );
        PHASE(1, 1, STAGE_B(s + 2, 0), VM4);
    }
    {
        const int bufb = ((NSK - 2) & 1) << 16;
        PHASE(0, 0, STAGE_A(NSK - 1, 1), );
        PHASE(0, 1, STAGE_B(NSK - 1, 1), );
        PHASE(1, 0, , );
        PHASE(1, 1, , VM0);
    }
    {
        const int bufb = ((NSK - 1) & 1) << 16;
        PHASE(0, 0, , );
        PHASE(0, 1, , );
        PHASE(1, 0, , );
        PHASE(1, 1, , );
    }

    const int r0 = m0 + wm * 128 + ((lane >> 4) << 2);
    const int c0 = n0 + wn * 64 + (lane & 15);
    if (OUTF32) {
        float* Co = Of + (long)z * zC;
#pragma unroll
        for (int mi = 0; mi < 8; ++mi)
#pragma unroll
            for (int nj = 0; nj < 4; ++nj)
#pragma unroll
                for (int r = 0; r < 4; ++r)
                    Co[(long)(r0 + mi * 16 + r) * N + c0 + nj * 16] =
                        acc[mi][nj][r];
    } else {
        const float* bs = z ? bias1 : bias0;
        float bc[4];
#pragma unroll
        for (int nj = 0; nj < 4; ++nj) bc[nj] = bs[c0 + nj * 16];
        u16* Oh = Ohi + (long)z * zC;
        u16* Ol = Olo + (long)z * zC;
#pragma unroll
        for (int mi = 0; mi < 8; ++mi)
#pragma unroll
            for (int nj = 0; nj < 4; ++nj)
#pragma unroll
                for (int r = 0; r < 4; ++r) {
                    float x = acc[mi][nj][r] + bc[nj];
                    long o = (long)(r0 + mi * 16 + r) * N + c0 + nj * 16;
                    u16 h = bf16rn(x);
                    Oh[o] = h;
                    Ol[o] = bf16rn(x - bf2f(h));
                }
    }
}

// ===========================================================================
// PV: 8-phase 256x128 NT GEMM. A = probs [2048][2048] bf16 (single plane),
// B = vT planes hi/lo [1024][2048] -> K' = 64 steps (steps 0-31 hi, 32-63 lo).
// 8 waves 2M x 4N, wave-tile 128x32. LDS 96 KiB (2 x {A 32K, B 16K}).
// ===========================================================================
#define PVNSK 64

#define PV_STAGE_A(T, mh) {                                                   \
    const char* _p = Ap + (long)((T) & 31) * 128;                             \
    char* _d = smem + (((T) & 1) * 49152) + ((mh) << 14) + (w << 10);         \
    gll16(_p + offA##mh##0, _d);                                              \
    gll16(_p + offA##mh##1, _d + 8192); }

#define PV_STAGE_B(T, nh) {                                                   \
    const char* _p = (((T) >> 5) ? Bl : Bh) + (long)((T) & 31) * 128;         \
    char* _d = smem + (((T) & 1) * 49152) + 32768 + ((nh) << 13) + (w << 10); \
    gll16(_p + offB##nh, _d); }

#define PVM3 { asm volatile("s_waitcnt vmcnt(3)" ::: "memory");               \
               __builtin_amdgcn_sched_barrier(0); }

#define PVPHASE(mh, nh, STAGE, ENDW)                                          \
  {                                                                           \
    if ((nh) == 0) {                                                          \
      _Pragma("unroll") for (int mi = 0; mi < 4; ++mi)                        \
        _Pragma("unroll") for (int ks = 0; ks < 2; ++ks)                      \
          afr[mi][ks] = *(const bf16x8*)(smem + bufb + ((mh) << 14) +         \
              aRdB + mi * 2048 + csw[ks]);                                    \
    }                                                                         \
    bf16x8 bfr[2];                                                            \
    _Pragma("unroll") for (int ks = 0; ks < 2; ++ks)                          \
      bfr[ks] = *(const bf16x8*)(smem + bufb + 32768 + ((nh) << 13) +         \
          bRdB + csw[ks]);                                                    \
    STAGE;                                                                    \
    __builtin_amdgcn_s_barrier();                                             \
    asm volatile("s_waitcnt lgkmcnt(0)" ::: "memory");                        \
    __builtin_amdgcn_sched_barrier(0);                                        \
    __builtin_amdgcn_s_setprio(1);                                            \
    _Pragma("unroll") for (int mi = 0; mi < 4; ++mi)                          \
      _Pragma("unroll") for (int ks = 0; ks < 2; ++ks)                        \
        acc[(mh) * 4 + mi][nh] =                                              \
            __builtin_amdgcn_mfma_f32_16x16x32_bf16(                          \
                afr[mi][ks], bfr[ks], acc[(mh) * 4 + mi][nh], 0, 0, 0);       \
    __builtin_amdgcn_s_setprio(0);                                            \
    ENDW;                                                                     \
    __builtin_amdgcn_s_barrier();                                             \
  }

__global__ __launch_bounds__(512, 2)
void gemm8pv(const char* pA, const char* vTh, const char* vTl,
             float* __restrict__ Of)
{
    extern __shared__ char smem[];
    const int t = threadIdx.x, lane = t & 63, w = t >> 6;
    const int wm = w >> 2, wn = w & 3;

    const int bid = blockIdx.x;
    const int xcd = bid & 7, bi = bid >> 3;
    const int z  = xcd >> 1;
    const int m0 = ((((xcd & 1) << 2) | (bi >> 3)) << 8);   // 8 M-tiles of 256
    const int n0 = (bi & 7) << 7;                           // 8 N-tiles of 128

    const char* Ap = pA  + (long)z * 8388608;   // 2048*2048*2B
    const char* Bh = vTh + (long)z * 4194304;   // 1024*2048*2B
    const char* Bl = vTl + (long)z * 4194304;

    const int lr0 = t >> 3;
    const long cg = (long)((((t & 7) ^ ((t >> 3) & 7)) << 4));
    const long offA00 = (long)(m0 + lr0) * 4096 + cg;        // row stride 2048 el
    const long offA01 = offA00 + 64L * 4096;
    const long offA10 = (long)(m0 + 128 + lr0) * 4096 + cg;
    const long offA11 = offA10 + 64L * 4096;
    const long offB0  = (long)(n0 + lr0) * 4096 + cg;
    const long offB1  = (long)(n0 + 64 + lr0) * 4096 + cg;

    const int swl = (lane & 7) << 4;
    const int csw[2] = { (((lane >> 4) << 4)) ^ swl,
                         (((lane >> 4) << 4) + 64) ^ swl };
    const int aRdB = (wm * 64 + (lane & 15)) * 128;
    const int bRdB = (wn * 16 + (lane & 15)) * 128;

    f32x4 acc[8][2];
#pragma unroll
    for (int i = 0; i < 8; ++i) { acc[i][0] = (f32x4)0.f; acc[i][1] = (f32x4)0.f; }
    bf16x8 afr[4][2];

    // prologue: tile0 (A0,A1,B0,B1 = 6 loads) + tile1 (A0,B0 = 3 loads)
    PV_STAGE_A(0, 0); PV_STAGE_B(0, 0); PV_STAGE_A(0, 1); PV_STAGE_B(0, 1);
    PV_STAGE_A(1, 0); PV_STAGE_B(1, 0);
    asm volatile("s_waitcnt vmcnt(3)" ::: "memory");
    __builtin_amdgcn_sched_barrier(0);
    __builtin_amdgcn_s_barrier();

    for (int s = 0; s < PVNSK - 2; ++s) {
        const int bufb = (s & 1) * 49152;
        PVPHASE(0, 0, PV_STAGE_A(s + 1, 1), );
        PVPHASE(0, 1, PV_STAGE_B(s + 1, 1), );
        PVPHASE(1, 0, PV_STAGE_A(s + 2, 0), );
        PVPHASE(1, 1, PV_STAGE_B(s + 2, 0), PVM3);
    }
    {
        const int bufb = ((PVNSK - 2) & 1) * 49152;
        PVPHASE(0, 0, PV_STAGE_A(PVNSK - 1, 1), );
        PVPHASE(0, 1, PV_STAGE_B(PVNSK - 1, 1), );
        PVPHASE(1, 0, , );
        PVPHASE(1, 1, , VM0);
    }
    {
        const int bufb = ((PVNSK - 1) & 1) * 49152;
        PVPHASE(0, 0, , );
        PVPHASE(0, 1, , );
        PVPHASE(1, 0, , );
        PVPHASE(1, 1, , );
    }

    float* Co = Of + (long)z * 2097152;
    const int r0 = m0 + wm * 64 + ((lane >> 4) << 2);
    const int c0 = n0 + wn * 16 + (lane & 15);
#pragma unroll
    for (int mh = 0; mh < 2; ++mh)
#pragma unroll
        for (int mi = 0; mi < 4; ++mi)
#pragma unroll
            for (int nh = 0; nh < 2; ++nh)
#pragma unroll
                for (int r = 0; r < 4; ++r)
                    Co[(long)(r0 + mh * 128 + mi * 16 + r) * 1024 +
                       c0 + nh * 64] = acc[mh * 4 + mi][nh][r];
}

// ---------------------------------------------------------------------------
__global__ __launch_bounds__(256)
void split_f32(const float* __restrict__ in, u16* __restrict__ hi, u16* __restrict__ lo)
{
    long i = ((long)blockIdx.x * 256 + threadIdx.x) * 4;
    float4 v = *(const float4*)(in + i);
    ushort4 h, l;
    h.x = bf16rn(v.x); l.x = bf16rn(v.x - bf2f(h.x));
    h.y = bf16rn(v.y); l.y = bf16rn(v.y - bf2f(h.y));
    h.z = bf16rn(v.z); l.z = bf16rn(v.z - bf2f(h.z));
    h.w = bf16rn(v.w); l.w = bf16rn(v.w - bf2f(h.w));
    *(ushort4*)(hi + i) = h;
    *(ushort4*)(lo + i) = l;
}

__global__ __launch_bounds__(256)
void tsplit_w(const float* __restrict__ W, u16* __restrict__ hi, u16* __restrict__ lo)
{
    __shared__ float tile[32][33];
    const int n0v = blockIdx.x * 32, k0 = blockIdx.y * 32;
    const int r = threadIdx.x >> 5, c = threadIdx.x & 31;
#pragma unroll
    for (int it = 0; it < 4; ++it)
        tile[r + it * 8][c] = W[(long)(k0 + r + it * 8) * 1024 + n0v + c];
    __syncthreads();
#pragma unroll
    for (int it = 0; it < 4; ++it) {
        const int rr = r + it * 8;
        float x = tile[c][rr];
        u16 h = bf16rn(x);
        long o = (long)(n0v + rr) * 1024 + k0 + c;
        hi[o] = h;
        lo[o] = bf16rn(x - bf2f(h));
    }
}

// merged vectorized transpose: z = batch*2 + plane; v[s][d] -> vT[d][s]
__global__ __launch_bounds__(256)
void tr2_bf16(const u16* __restrict__ v_hi, const u16* __restrict__ v_lo,
              u16* __restrict__ vT_hi, u16* __restrict__ vT_lo)
{
    __shared__ u16 tile[64][68];
    const int pl = blockIdx.z & 1, b = blockIdx.z >> 1;
    const u16* src = (pl ? v_lo : v_hi) + (long)b * 2097152;
    u16* dst = (pl ? vT_lo : vT_hi) + (long)b * 2097152;
    const int s0 = blockIdx.x * 64, d0 = blockIdx.y * 64;
    const int t = threadIdx.x;
    const int rr = t >> 4, c4 = (t & 15) * 4;
#pragma unroll
    for (int it = 0; it < 4; ++it) {
        const int s = it * 16 + rr;
        *(short4*)&tile[s][c4] =
            *(const short4*)(src + (long)(s0 + s) * 1024 + d0 + c4);
    }
    __syncthreads();
#pragma unroll
    for (int it = 0; it < 4; ++it) {
        const int d = it * 16 + rr;
        short4 o;
        o.x = tile[c4 + 0][d]; o.y = tile[c4 + 1][d];
        o.z = tile[c4 + 2][d]; o.w = tile[c4 + 3][d];
        *(short4*)(dst + (long)(d0 + d) * 2048 + s0 + c4) = o;
    }
}

__global__ __launch_bounds__(256)
void softmax_p(const float* __restrict__ S, u16* __restrict__ P)
{
    const float* p = S + (long)blockIdx.x * 2048;
    u16* o = P + (long)blockIdx.x * 2048;
    const int t = threadIdx.x;

    float4 x0 = *(const float4*)&p[t * 4];
    float4 x1 = *(const float4*)&p[1024 + t * 4];

    float mx = fmaxf(fmaxf(fmaxf(x0.x, x0.y), fmaxf(x0.z, x0.w)),
                     fmaxf(fmaxf(x1.x, x1.y), fmaxf(x1.z, x1.w)));
#pragma unroll
    for (int off = 32; off; off >>= 1) mx = fmaxf(mx, __shfl_xor(mx, off));

    __shared__ float red[8];
    if ((t & 63) == 0) red[t >> 6] = mx;
    __syncthreads();
    mx = fmaxf(fmaxf(red[0], red[1]), fmaxf(red[2], red[3]));

    x0.x = __expf(x0.x - mx); x0.y = __expf(x0.y - mx);
    x0.z = __expf(x0.z - mx); x0.w = __expf(x0.w - mx);
    x1.x = __expf(x1.x - mx); x1.y = __expf(x1.y - mx);
    x1.z = __expf(x1.z - mx); x1.w = __expf(x1.w - mx);

    float sm2 = (x0.x + x0.y + x0.z + x0.w) + (x1.x + x1.y + x1.z + x1.w);
#pragma unroll
    for (int off = 32; off; off >>= 1) sm2 += __shfl_xor(sm2, off);
    if ((t & 63) == 0) red[4 + (t >> 6)] = sm2;
    __syncthreads();
    sm2 = (red[4] + red[5]) + (red[6] + red[7]);

    const float inv = 1.0f / sm2;
    ushort4 y;
    y.x = bf16rn(x0.x * inv); y.y = bf16rn(x0.y * inv);
    y.z = bf16rn(x0.z * inv); y.w = bf16rn(x0.w * inv);
    *(ushort4*)(o + t * 4) = y;
    y.x = bf16rn(x1.x * inv); y.y = bf16rn(x1.y * inv);
    y.z = bf16rn(x1.z * inv); y.w = bf16rn(x1.w * inv);
    *(ushort4*)(o + 1024 + t * 4) = y;
}

// ---------------------------------------------------------------------------
// ws layout (MiB): [0,64) qx_hi,qx_lo,vx_hi,vx_lo (16 each) -> later sc fp32;
// [64,96) q_hi,q_lo -> later p bf16; [96,128) v_hi,v_lo; [128,160) vT_hi,vT_lo;
// [160,168) WqT_hi,WqT_lo,WvT_hi,WvT_lo. Total 168 MB.
// ---------------------------------------------------------------------------
extern "C" void kernel_launch(void* const* d_in, const int* in_sizes, int n_in,
                              void* d_out, int out_size, void* d_ws, size_t ws_size,
                              hipStream_t stream)
{
    const float* query = (const float*)d_in[0];
    const float* value = (const float*)d_in[1];
    const float* Wq    = (const float*)d_in[2];
    const float* bq    = (const float*)d_in[3];
    const float* Wv    = (const float*)d_in[4];
    const float* bv    = (const float*)d_in[5];
    float* out = (float*)d_out;

    char* W = (char*)d_ws;
    u16* qx_hi = (u16*)(W);
    u16* qx_lo = qx_hi + 8388608;
    u16* vx_hi = qx_lo + 8388608;
    u16* vx_lo = vx_hi + 8388608;
    float* sc  = (float*)W;                       // overlaps qx/vx (dead by then)
    u16* q_hi  = (u16*)(W + 67108864);
    u16* q_lo  = q_hi + 8388608;
    u16* p     = (u16*)(W + 67108864);            // overlaps q_hi/q_lo (dead by then)
    u16* v_hi  = (u16*)(W + 100663296);
    u16* v_lo  = v_hi + 8388608;
    u16* vT_hi = (u16*)(W + 134217728);
    u16* vT_lo = vT_hi + 8388608;
    u16* WqT_hi = (u16*)(W + 167772160);
    u16* WqT_lo = WqT_hi + 1048576;
    u16* WvT_hi = WqT_lo + 1048576;
    u16* WvT_lo = WvT_hi + 1048576;

    hipFuncSetAttribute((const void*)&gemm8<false, 1>,
                        hipFuncAttributeMaxDynamicSharedMemorySize, 131072);
    hipFuncSetAttribute((const void*)&gemm8<true, 0>,
                        hipFuncAttributeMaxDynamicSharedMemorySize, 131072);
    hipFuncSetAttribute((const void*)&gemm8pv,
                        hipFuncAttributeMaxDynamicSharedMemorySize, 98304);

    // input splits
    split_f32<<<8192, 256, 0, stream>>>(query, qx_hi, qx_lo);
    split_f32<<<8192, 256, 0, stream>>>(value, vx_hi, vx_lo);
    tsplit_w<<<dim3(32, 32), 256, 0, stream>>>(Wq, WqT_hi, WqT_lo);
    tsplit_w<<<dim3(32, 32), 256, 0, stream>>>(Wv, WvT_hi, WvT_lo);

    // fused projections (z=0: q, z=1: v): planes A=[x_hi,x_hi,x_lo],
    // B=[W_hi,W_lo,W_hi]; out bf16 hi/lo (+bias)
    gemm8<false, 1><<<256, 512, 131072, stream>>>(
        (const char*)qx_hi, (const char*)qx_hi, (const char*)qx_lo, 33554432L,
        (const char*)WqT_hi, (const char*)WqT_lo, (const char*)WqT_hi, 4194304L,
        nullptr, q_hi, q_lo, 16777216L, bq, bv, 1024);

    // v^T (both planes, one launch)
    tr2_bf16<<<dim3(32, 16, 8), 256, 0, stream>>>(v_hi, v_lo, vT_hi, vT_lo);

    // scores: per batch, planes A=[q_hi,q_hi,q_lo], B=[v_hi,v_lo,v_hi] -> fp32
    gemm8<true, 0><<<256, 512, 131072, stream>>>(
        (const char*)q_hi, (const char*)q_hi, (const char*)q_lo, 4194304L,
        (const char*)v_hi, (const char*)v_lo, (const char*)v_hi, 4194304L,
        sc, nullptr, nullptr, 4194304L, nullptr, nullptr, 2048);

    softmax_p<<<8192, 256, 0, stream>>>(sc, p);

    // context: per batch [2048,2048] @ [1024,2048]^T (2 planes) -> fp32 out
    gemm8pv<<<256, 512, 98304, stream>>>(
        (const char*)p, (const char*)vT_hi, (const char*)vT_lo, out);
}

// Round 6
// 393.522 us; speedup vs baseline: 3.3804x; 1.0587x over previous
//
#include <hip/hip_runtime.h>
#include <hip/hip_bf16.h>

// Problem: B=4, S=2048, HIDDEN=ATTN=1024.
// q = query@Wq + bq ; v = value@Wv + bv ; sc = q@v^T ; p = softmax(sc) ; out = p@v
// All GEMMs bf16 hi/lo-split MFMA, 8-phase pipelined 256-wide-tile kernels
// (T2 swizzle + T3/T4 counted vmcnt + T5 setprio + T1 XCD-chunked grid).
// R6: B-fragment register caching (LDS reads/step 32->24 gemm8, 24->20 PV),
// merged aux launches.

typedef unsigned short u16;
typedef __attribute__((ext_vector_type(8))) short bf16x8;  // 4 VGPRs
typedef __attribute__((ext_vector_type(4))) float f32x4;

typedef __attribute__((address_space(1))) void gvoid_t;
typedef __attribute__((address_space(3))) void svoid_t;

__device__ __forceinline__ void gll16(const void* g, void* l) {
    __builtin_amdgcn_global_load_lds((gvoid_t*)g, (svoid_t*)l, 16, 0, 0);
}

__device__ __forceinline__ u16 bf16rn(float x) {
    unsigned u = __float_as_uint(x);
    unsigned r = (u + 0x7FFFu + ((u >> 16) & 1u)) >> 16;
    return (u16)r;
}
__device__ __forceinline__ float bf2f(u16 h) {
    return __uint_as_float(((unsigned)h) << 16);
}

__device__ __forceinline__ const char* sel3(const char* p0, const char* p1,
                                            const char* p2, int i) {
    return i == 0 ? p0 : (i == 1 ? p1 : p2);
}

// ===========================================================================
// 8-phase 256x256 NT GEMM, BK=64, 512 thr = 8 waves (2M x 4N), LDS 128 KiB.
// K' = 48 steps = 3 planes of 1024 (plane row stride fixed 2048 B).
// SCHEME: XCD-chunked flat-grid decode. 0: (x8,y8,z4)  1: (x4,y32,z2).
// Phase schedule with B-reg caching (reads/step = 16 A + 8 B = 24 b128):
//   ph0 (0,0): read afr[mh0]+b0r ; stage A1(s+1)
//   ph1 (0,1): read b1r          ; stage B1(s+1)
//   ph2 (1,0): read afr[mh1]     ; stage A0(s+2)   (b0r reused)
//   ph3 (1,1): no reads          ; stage B0(s+2)+VM4 (b1r reused)
// ===========================================================================
#define NSK 48

#define STAGE_A(T, mh) {                                                      \
    const char* _p = sel3(A0z, A1z, A2z, (T) >> 4) + (long)((T) & 15) * 128;  \
    char* _d = smem + (((T) & 1) << 16) + ((mh) << 14) + (w << 10);           \
    gll16(_p + offA##mh##0, _d);                                              \
    gll16(_p + offA##mh##1, _d + 8192); }

#define STAGE_B(T, nh) {                                                      \
    const char* _p = sel3(B0z, B1z, B2z, (T) >> 4) + (long)((T) & 15) * 128;  \
    char* _d = smem + (((T) & 1) << 16) + 32768 + ((nh) << 14) + (w << 10);   \
    gll16(_p + offB##nh##0, _d);                                              \
    gll16(_p + offB##nh##1, _d + 8192); }

#define VM4 { asm volatile("s_waitcnt vmcnt(4)" ::: "memory");                \
              __builtin_amdgcn_sched_barrier(0); }
#define VM0 { asm volatile("s_waitcnt vmcnt(0)" ::: "memory");                \
              __builtin_amdgcn_sched_barrier(0); }

#define PHASE(mh, nh, RDA, RDB, BFR, STAGE, ENDW)                             \
  {                                                                           \
    if (RDA) {                                                                \
      _Pragma("unroll") for (int mi = 0; mi < 4; ++mi)                        \
        _Pragma("unroll") for (int ks = 0; ks < 2; ++ks)                      \
          afr[mi][ks] = *(const bf16x8*)(smem + bufb + ((mh) << 14) +         \
              aRdB + mi * 2048 + csw[ks]);                                    \
    }                                                                         \
    if (RDB) {                                                                \
      _Pragma("unroll") for (int ni = 0; ni < 2; ++ni)                        \
        _Pragma("unroll") for (int ks = 0; ks < 2; ++ks)                      \
          BFR[ni][ks] = *(const bf16x8*)(smem + bufb + ((nh) << 14) +         \
              bRdB + ni * 2048 + csw[ks]);                                    \
    }                                                                         \
    STAGE;                                                                    \
    __builtin_amdgcn_s_barrier();                                             \
    asm volatile("s_waitcnt lgkmcnt(0)" ::: "memory");                        \
    __builtin_amdgcn_sched_barrier(0);                                        \
    __builtin_amdgcn_s_setprio(1);                                            \
    _Pragma("unroll") for (int mi = 0; mi < 4; ++mi)                          \
      _Pragma("unroll") for (int ni = 0; ni < 2; ++ni)                        \
        _Pragma("unroll") for (int ks = 0; ks < 2; ++ks)                      \
          acc[(mh) * 4 + mi][(nh) * 2 + ni] =                                 \
              __builtin_amdgcn_mfma_f32_16x16x32_bf16(                        \
                  afr[mi][ks], BFR[ni][ks],                                   \
                  acc[(mh) * 4 + mi][(nh) * 2 + ni], 0, 0, 0);                \
    __builtin_amdgcn_s_setprio(0);                                            \
    ENDW;                                                                     \
    __builtin_amdgcn_s_barrier();                                             \
  }

template<bool OUTF32, int SCHEME>
__global__ __launch_bounds__(512, 2)
void gemm8(const char* a0, const char* a1, const char* a2, long zA,
           const char* b0, const char* b1, const char* b2, long zB,
           float* __restrict__ Of, u16* __restrict__ Ohi, u16* __restrict__ Olo,
           long zC, const float* __restrict__ bias0,
           const float* __restrict__ bias1, int N)
{
    extern __shared__ char smem[];
    const int t = threadIdx.x, lane = t & 63, w = t >> 6;
    const int wm = w >> 2, wn = w & 3;

    // T1: XCD-chunked decode (bid%8 = XCD round-robin assumption; perf-only)
    const int bid = blockIdx.x;
    const int xcd = bid & 7, bi = bid >> 3;
    int m0, n0, z;
    if (SCHEME == 0) {            // scores: x=8 N-tiles, y=8 M-tiles, z=4
        z = xcd >> 1;
        m0 = (((xcd & 1) << 2) | (bi >> 3)) << 8;
        n0 = (bi & 7) << 8;
    } else {                      // proj: x=4, y=32, z=2
        m0 = ((xcd << 2) | (bi >> 3)) << 8;
        n0 = (bi & 3) << 8;
        z = (bi >> 2) & 1;
    }

    const char* A0z = a0 + (long)z * zA;
    const char* A1z = a1 + (long)z * zA;
    const char* A2z = a2 + (long)z * zA;
    const char* B0z = b0 + (long)z * zB;
    const char* B1z = b1 + (long)z * zB;
    const char* B2z = b2 + (long)z * zB;

    // staging: LDS linear (lr, c) <- global (grow, c ^ ((lr&7)<<4))
    const int lr0 = t >> 3;
    const long cg = (long)((((t & 7) ^ ((t >> 3) & 7)) << 4));
    const long offA00 = (long)(m0 + lr0) * 2048 + cg;
    const long offA01 = offA00 + 128L * 2048;
    const long offA10 = (long)(m0 + 64 + lr0) * 2048 + cg;
    const long offA11 = offA10 + 128L * 2048;
    const long offB00 = (long)(n0 + ((lr0 >> 5) << 6) + (lr0 & 31)) * 2048 + cg;
    const long offB01 = offB00 + 128L * 2048;
    const long offB10 = offB00 + 32L * 2048;
    const long offB11 = offB10 + 128L * 2048;

    const int swl = (lane & 7) << 4;
    const int csw[2] = { (((lane >> 4) << 4)) ^ swl,
                         (((lane >> 4) << 4) + 64) ^ swl };
    const int aRdB = (wm * 64 + (lane & 15)) * 128;
    const int bRdB = 32768 + (wn * 32 + (lane & 15)) * 128;

    f32x4 acc[8][4];
#pragma unroll
    for (int i = 0; i < 8; ++i)
#pragma unroll
        for (int j = 0; j < 4; ++j) acc[i][j] = (f32x4)0.f;
    bf16x8 afr[4][2];
    bf16x8 b0r[2][2], b1r[2][2];

    STAGE_A(0, 0); STAGE_B(0, 0); STAGE_A(0, 1); STAGE_B(0, 1);
    STAGE_A(1, 0); STAGE_B(1, 0);
    asm volatile("s_waitcnt vmcnt(4)" ::: "memory");
    __builtin_amdgcn_sched_barrier(0);
    __builtin_amdgcn_s_barrier();

    for (int s = 0; s < NSK - 2; ++s) {
        const int bufb = (s & 1) << 16;
        PHASE(0, 0, 1, 1, b0r, STAGE_A(s + 1, 1), );
        PHASE(0, 1, 0, 1, b1r, STAGE_B(s + 1, 1), );
        PHASE(1, 0, 1, 0, b0r, STAGE_A(s + 2, 0), );
        PHASE(1, 1, 0, 0, b1r, STAGE_B(s + 2, 0), VM4);
    }
    {
        const int bufb = ((NSK - 2) & 1) << 16;
        PHASE(0, 0, 1, 1, b0r, STAGE_A(NSK - 1, 1), );
        PHASE(0, 1, 0, 1, b1r, STAGE_B(NSK - 1, 1), );
        PHASE(1, 0, 1, 0, b0r, , );
        PHASE(1, 1, 0, 0, b1r, , VM0);
    }
    {
        const int bufb = ((NSK - 1) & 1) << 16;
        PHASE(0, 0, 1, 1, b0r, , );
        PHASE(0, 1, 0, 1, b1r, , );
        PHASE(1, 0, 1, 0, b0r, , );
        PHASE(1, 1, 0, 0, b1r, , );
    }

    const int r0 = m0 + wm * 128 + ((lane >> 4) << 2);
    const int c0 = n0 + wn * 64 + (lane & 15);
    if (OUTF32) {
        float* Co = Of + (long)z * zC;
#pragma unroll
        for (int mi = 0; mi < 8; ++mi)
#pragma unroll
            for (int nj = 0; nj < 4; ++nj)
#pragma unroll
                for (int r = 0; r < 4; ++r)
                    Co[(long)(r0 + mi * 16 + r) * N + c0 + nj * 16] =
                        acc[mi][nj][r];
    } else {
        const float* bs = z ? bias1 : bias0;
        float bc[4];
#pragma unroll
        for (int nj = 0; nj < 4; ++nj) bc[nj] = bs[c0 + nj * 16];
        u16* Oh = Ohi + (long)z * zC;
        u16* Ol = Olo + (long)z * zC;
#pragma unroll
        for (int mi = 0; mi < 8; ++mi)
#pragma unroll
            for (int nj = 0; nj < 4; ++nj)
#pragma unroll
                for (int r = 0; r < 4; ++r) {
                    float x = acc[mi][nj][r] + bc[nj];
                    long o = (long)(r0 + mi * 16 + r) * N + c0 + nj * 16;
                    u16 h = bf16rn(x);
                    Oh[o] = h;
                    Ol[o] = bf16rn(x - bf2f(h));
                }
    }
}

// ===========================================================================
// PV: 8-phase 256x128 NT GEMM. A = probs [2048][2048] bf16 (single plane),
// B = vT planes hi/lo [1024][2048] -> K' = 64 steps (steps 0-31 hi, 32-63 lo).
// 8 waves 2M x 4N, wave-tile 128x32. LDS 96 KiB (2 x {A 32K, B 16K}).
// B-reg caching: bA read ph0 (reused ph2), bB read ph1 (reused ph3).
// ===========================================================================
#define PVNSK 64

#define PV_STAGE_A(T, mh) {                                                   \
    const char* _p = Ap + (long)((T) & 31) * 128;                             \
    char* _d = smem + (((T) & 1) * 49152) + ((mh) << 14) + (w << 10);         \
    gll16(_p + offA##mh##0, _d);                                              \
    gll16(_p + offA##mh##1, _d + 8192); }

#define PV_STAGE_B(T, nh) {                                                   \
    const char* _p = (((T) >> 5) ? Bl : Bh) + (long)((T) & 31) * 128;         \
    char* _d = smem + (((T) & 1) * 49152) + 32768 + ((nh) << 13) + (w << 10); \
    gll16(_p + offB##nh, _d); }

#define PVM3 { asm volatile("s_waitcnt vmcnt(3)" ::: "memory");               \
               __builtin_amdgcn_sched_barrier(0); }

#define PVPHASE(mh, nh, RDA, RDB, BFR, STAGE, ENDW)                           \
  {                                                                           \
    if (RDA) {                                                                \
      _Pragma("unroll") for (int mi = 0; mi < 4; ++mi)                        \
        _Pragma("unroll") for (int ks = 0; ks < 2; ++ks)                      \
          afr[mi][ks] = *(const bf16x8*)(smem + bufb + ((mh) << 14) +         \
              aRdB + mi * 2048 + csw[ks]);                                    \
    }                                                                         \
    if (RDB) {                                                                \
      _Pragma("unroll") for (int ks = 0; ks < 2; ++ks)                        \
        BFR[ks] = *(const bf16x8*)(smem + bufb + 32768 + ((nh) << 13) +       \
            bRdB + csw[ks]);                                                  \
    }                                                                         \
    STAGE;                                                                    \
    __builtin_amdgcn_s_barrier();                                             \
    asm volatile("s_waitcnt lgkmcnt(0)" ::: "memory");                        \
    __builtin_amdgcn_sched_barrier(0);                                        \
    __builtin_amdgcn_s_setprio(1);                                            \
    _Pragma("unroll") for (int mi = 0; mi < 4; ++mi)                          \
      _Pragma("unroll") for (int ks = 0; ks < 2; ++ks)                        \
        acc[(mh) * 4 + mi][nh] =                                              \
            __builtin_amdgcn_mfma_f32_16x16x32_bf16(                          \
                afr[mi][ks], BFR[ks], acc[(mh) * 4 + mi][nh], 0, 0, 0);       \
    __builtin_amdgcn_s_setprio(0);                                            \
    ENDW;                                                                     \
    __builtin_amdgcn_s_barrier();                                             \
  }

__global__ __launch_bounds__(512, 2)
void gemm8pv(const char* pA, const char* vTh, const char* vTl,
             float* __restrict__ Of)
{
    extern __shared__ char smem[];
    const int t = threadIdx.x, lane = t & 63, w = t >> 6;
    const int wm = w >> 2, wn = w & 3;

    const int bid = blockIdx.x;
    const int xcd = bid & 7, bi = bid >> 3;
    const int z  = xcd >> 1;
    const int m0 = ((((xcd & 1) << 2) | (bi >> 3)) << 8);   // 8 M-tiles of 256
    const int n0 = (bi & 7) << 7;                           // 8 N-tiles of 128

    const char* Ap = pA  + (long)z * 8388608;   // 2048*2048*2B
    const char* Bh = vTh + (long)z * 4194304;   // 1024*2048*2B
    const char* Bl = vTl + (long)z * 4194304;

    const int lr0 = t >> 3;
    const long cg = (long)((((t & 7) ^ ((t >> 3) & 7)) << 4));
    const long offA00 = (long)(m0 + lr0) * 4096 + cg;        // row stride 2048 el
    const long offA01 = offA00 + 64L * 4096;
    const long offA10 = (long)(m0 + 128 + lr0) * 4096 + cg;
    const long offA11 = offA10 + 64L * 4096;
    const long offB0  = (long)(n0 + lr0) * 4096 + cg;
    const long offB1  = (long)(n0 + 64 + lr0) * 4096 + cg;

    const int swl = (lane & 7) << 4;
    const int csw[2] = { (((lane >> 4) << 4)) ^ swl,
                         (((lane >> 4) << 4) + 64) ^ swl };
    const int aRdB = (wm * 64 + (lane & 15)) * 128;
    const int bRdB = (wn * 16 + (lane & 15)) * 128;

    f32x4 acc[8][2];
#pragma unroll
    for (int i = 0; i < 8; ++i) { acc[i][0] = (f32x4)0.f; acc[i][1] = (f32x4)0.f; }
    bf16x8 afr[4][2];
    bf16x8 bA[2], bB[2];

    // prologue: tile0 (A0,A1,B0,B1 = 6 loads) + tile1 (A0,B0 = 3 loads)
    PV_STAGE_A(0, 0); PV_STAGE_B(0, 0); PV_STAGE_A(0, 1); PV_STAGE_B(0, 1);
    PV_STAGE_A(1, 0); PV_STAGE_B(1, 0);
    asm volatile("s_waitcnt vmcnt(3)" ::: "memory");
    __builtin_amdgcn_sched_barrier(0);
    __builtin_amdgcn_s_barrier();

    for (int s = 0; s < PVNSK - 2; ++s) {
        const int bufb = (s & 1) * 49152;
        PVPHASE(0, 0, 1, 1, bA, PV_STAGE_A(s + 1, 1), );
        PVPHASE(0, 1, 0, 1, bB, PV_STAGE_B(s + 1, 1), );
        PVPHASE(1, 0, 1, 0, bA, PV_STAGE_A(s + 2, 0), );
        PVPHASE(1, 1, 0, 0, bB, PV_STAGE_B(s + 2, 0), PVM3);
    }
    {
        const int bufb = ((PVNSK - 2) & 1) * 49152;
        PVPHASE(0, 0, 1, 1, bA, PV_STAGE_A(PVNSK - 1, 1), );
        PVPHASE(0, 1, 0, 1, bB, PV_STAGE_B(PVNSK - 1, 1), );
        PVPHASE(1, 0, 1, 0, bA, , );
        PVPHASE(1, 1, 0, 0, bB, , VM0);
    }
    {
        const int bufb = ((PVNSK - 1) & 1) * 49152;
        PVPHASE(0, 0, 1, 1, bA, , );
        PVPHASE(0, 1, 0, 1, bB, , );
        PVPHASE(1, 0, 1, 0, bA, , );
        PVPHASE(1, 1, 0, 0, bB, , );
    }

    float* Co = Of + (long)z * 2097152;
    const int r0 = m0 + wm * 64 + ((lane >> 4) << 2);
    const int c0 = n0 + wn * 16 + (lane & 15);
#pragma unroll
    for (int mh = 0; mh < 2; ++mh)
#pragma unroll
        for (int mi = 0; mi < 4; ++mi)
#pragma unroll
            for (int nh = 0; nh < 2; ++nh)
#pragma unroll
                for (int r = 0; r < 4; ++r)
                    Co[(long)(r0 + mh * 128 + mi * 16 + r) * 1024 +
                       c0 + nh * 64] = acc[mh * 4 + mi][nh][r];
}

// ---------------------------------------------------------------------------
// merged fp32 -> bf16 hi/lo split for query+value. grid (8192, 2).
// ---------------------------------------------------------------------------
__global__ __launch_bounds__(256)
void split2_f32(const float* __restrict__ q, const float* __restrict__ v,
                u16* __restrict__ qh, u16* __restrict__ ql,
                u16* __restrict__ vh, u16* __restrict__ vl)
{
    const int sel = blockIdx.y;
    const float* in = sel ? v : q;
    u16* hi = sel ? vh : qh;
    u16* lo = sel ? vl : ql;
    long i = ((long)blockIdx.x * 256 + threadIdx.x) * 4;
    float4 x = *(const float4*)(in + i);
    ushort4 h, l;
    h.x = bf16rn(x.x); l.x = bf16rn(x.x - bf2f(h.x));
    h.y = bf16rn(x.y); l.y = bf16rn(x.y - bf2f(h.y));
    h.z = bf16rn(x.z); l.z = bf16rn(x.z - bf2f(h.z));
    h.w = bf16rn(x.w); l.w = bf16rn(x.w - bf2f(h.w));
    *(ushort4*)(hi + i) = h;
    *(ushort4*)(lo + i) = l;
}

// merged W transpose+split: grid (32, 32, 2); z picks Wq/Wv.
__global__ __launch_bounds__(256)
void tsplit2_w(const float* __restrict__ Wq, const float* __restrict__ Wv,
               u16* __restrict__ qhi, u16* __restrict__ qlo,
               u16* __restrict__ vhi, u16* __restrict__ vlo)
{
    __shared__ float tile[32][33];
    const int sel = blockIdx.z;
    const float* W = sel ? Wv : Wq;
    u16* hi = sel ? vhi : qhi;
    u16* lo = sel ? vlo : qlo;
    const int n0v = blockIdx.x * 32, k0 = blockIdx.y * 32;
    const int r = threadIdx.x >> 5, c = threadIdx.x & 31;
#pragma unroll
    for (int it = 0; it < 4; ++it)
        tile[r + it * 8][c] = W[(long)(k0 + r + it * 8) * 1024 + n0v + c];
    __syncthreads();
#pragma unroll
    for (int it = 0; it < 4; ++it) {
        const int rr = r + it * 8;
        float x = tile[c][rr];
        u16 h = bf16rn(x);
        long o = (long)(n0v + rr) * 1024 + k0 + c;
        hi[o] = h;
        lo[o] = bf16rn(x - bf2f(h));
    }
}

// merged vectorized transpose: z = batch*2 + plane; v[s][d] -> vT[d][s]
__global__ __launch_bounds__(256)
void tr2_bf16(const u16* __restrict__ v_hi, const u16* __restrict__ v_lo,
              u16* __restrict__ vT_hi, u16* __restrict__ vT_lo)
{
    __shared__ u16 tile[64][68];
    const int pl = blockIdx.z & 1, b = blockIdx.z >> 1;
    const u16* src = (pl ? v_lo : v_hi) + (long)b * 2097152;
    u16* dst = (pl ? vT_lo : vT_hi) + (long)b * 2097152;
    const int s0 = blockIdx.x * 64, d0 = blockIdx.y * 64;
    const int t = threadIdx.x;
    const int rr = t >> 4, c4 = (t & 15) * 4;
#pragma unroll
    for (int it = 0; it < 4; ++it) {
        const int s = it * 16 + rr;
        *(short4*)&tile[s][c4] =
            *(const short4*)(src + (long)(s0 + s) * 1024 + d0 + c4);
    }
    __syncthreads();
#pragma unroll
    for (int it = 0; it < 4; ++it) {
        const int d = it * 16 + rr;
        short4 o;
        o.x = tile[c4 + 0][d]; o.y = tile[c4 + 1][d];
        o.z = tile[c4 + 2][d]; o.w = tile[c4 + 3][d];
        *(short4*)(dst + (long)(d0 + d) * 2048 + s0 + c4) = o;
    }
}

__global__ __launch_bounds__(256)
void softmax_p(const float* __restrict__ S, u16* __restrict__ P)
{
    const float* p = S + (long)blockIdx.x * 2048;
    u16* o = P + (long)blockIdx.x * 2048;
    const int t = threadIdx.x;

    float4 x0 = *(const float4*)&p[t * 4];
    float4 x1 = *(const float4*)&p[1024 + t * 4];

    float mx = fmaxf(fmaxf(fmaxf(x0.x, x0.y), fmaxf(x0.z, x0.w)),
                     fmaxf(fmaxf(x1.x, x1.y), fmaxf(x1.z, x1.w)));
#pragma unroll
    for (int off = 32; off; off >>= 1) mx = fmaxf(mx, __shfl_xor(mx, off));

    __shared__ float red[8];
    if ((t & 63) == 0) red[t >> 6] = mx;
    __syncthreads();
    mx = fmaxf(fmaxf(red[0], red[1]), fmaxf(red[2], red[3]));

    x0.x = __expf(x0.x - mx); x0.y = __expf(x0.y - mx);
    x0.z = __expf(x0.z - mx); x0.w = __expf(x0.w - mx);
    x1.x = __expf(x1.x - mx); x1.y = __expf(x1.y - mx);
    x1.z = __expf(x1.z - mx); x1.w = __expf(x1.w - mx);

    float sm2 = (x0.x + x0.y + x0.z + x0.w) + (x1.x + x1.y + x1.z + x1.w);
#pragma unroll
    for (int off = 32; off; off >>= 1) sm2 += __shfl_xor(sm2, off);
    if ((t & 63) == 0) red[4 + (t >> 6)] = sm2;
    __syncthreads();
    sm2 = (red[4] + red[5]) + (red[6] + red[7]);

    const float inv = 1.0f / sm2;
    ushort4 y;
    y.x = bf16rn(x0.x * inv); y.y = bf16rn(x0.y * inv);
    y.z = bf16rn(x0.z * inv); y.w = bf16rn(x0.w * inv);
    *(ushort4*)(o + t * 4) = y;
    y.x = bf16rn(x1.x * inv); y.y = bf16rn(x1.y * inv);
    y.z = bf16rn(x1.z * inv); y.w = bf16rn(x1.w * inv);
    *(ushort4*)(o + 1024 + t * 4) = y;
}

// ---------------------------------------------------------------------------
// ws layout (MiB): [0,64) qx_hi,qx_lo,vx_hi,vx_lo (16 each) -> later sc fp32;
// [64,96) q_hi,q_lo -> later p bf16; [96,128) v_hi,v_lo; [128,160) vT_hi,vT_lo;
// [160,168) WqT_hi,WqT_lo,WvT_hi,WvT_lo. Total 168 MB.
// ---------------------------------------------------------------------------
extern "C" void kernel_launch(void* const* d_in, const int* in_sizes, int n_in,
                              void* d_out, int out_size, void* d_ws, size_t ws_size,
                              hipStream_t stream)
{
    const float* query = (const float*)d_in[0];
    const float* value = (const float*)d_in[1];
    const float* Wq    = (const float*)d_in[2];
    const float* bq    = (const float*)d_in[3];
    const float* Wv    = (const float*)d_in[4];
    const float* bv    = (const float*)d_in[5];
    float* out = (float*)d_out;

    char* W = (char*)d_ws;
    u16* qx_hi = (u16*)(W);
    u16* qx_lo = qx_hi + 8388608;
    u16* vx_hi = qx_lo + 8388608;
    u16* vx_lo = vx_hi + 8388608;
    float* sc  = (float*)W;                       // overlaps qx/vx (dead by then)
    u16* q_hi  = (u16*)(W + 67108864);
    u16* q_lo  = q_hi + 8388608;
    u16* p     = (u16*)(W + 67108864);            // overlaps q_hi/q_lo (dead by then)
    u16* v_hi  = (u16*)(W + 100663296);
    u16* v_lo  = v_hi + 8388608;
    u16* vT_hi = (u16*)(W + 134217728);
    u16* vT_lo = vT_hi + 8388608;
    u16* WqT_hi = (u16*)(W + 167772160);
    u16* WqT_lo = WqT_hi + 1048576;
    u16* WvT_hi = WqT_lo + 1048576;
    u16* WvT_lo = WvT_hi + 1048576;

    hipFuncSetAttribute((const void*)&gemm8<false, 1>,
                        hipFuncAttributeMaxDynamicSharedMemorySize, 131072);
    hipFuncSetAttribute((const void*)&gemm8<true, 0>,
                        hipFuncAttributeMaxDynamicSharedMemorySize, 131072);
    hipFuncSetAttribute((const void*)&gemm8pv,
                        hipFuncAttributeMaxDynamicSharedMemorySize, 98304);

    // input splits (merged launches)
    split2_f32<<<dim3(8192, 2), 256, 0, stream>>>(query, value,
                                                  qx_hi, qx_lo, vx_hi, vx_lo);
    tsplit2_w<<<dim3(32, 32, 2), 256, 0, stream>>>(Wq, Wv,
                                                   WqT_hi, WqT_lo, WvT_hi, WvT_lo);

    // fused projections (z=0: q, z=1: v): planes A=[x_hi,x_hi,x_lo],
    // B=[W_hi,W_lo,W_hi]; out bf16 hi/lo (+bias)
    gemm8<false, 1><<<256, 512, 131072, stream>>>(
        (const char*)qx_hi, (const char*)qx_hi, (const char*)qx_lo, 33554432L,
        (const char*)WqT_hi, (const char*)WqT_lo, (const char*)WqT_hi, 4194304L,
        nullptr, q_hi, q_lo, 16777216L, bq, bv, 1024);

    // v^T (both planes, one launch)
    tr2_bf16<<<dim3(32, 16, 8), 256, 0, stream>>>(v_hi, v_lo, vT_hi, vT_lo);

    // scores: per batch, planes A=[q_hi,q_hi,q_lo], B=[v_hi,v_lo,v_hi] -> fp32
    gemm8<true, 0><<<256, 512, 131072, stream>>>(
        (const char*)q_hi, (const char*)q_hi, (const char*)q_lo, 4194304L,
        (const char*)v_hi, (const char*)v_lo, (const char*)v_hi, 4194304L,
        sc, nullptr, nullptr, 4194304L, nullptr, nullptr, 2048);

    softmax_p<<<8192, 256, 0, stream>>>(sc, p);

    // context: per batch [2048,2048] @ [1024,2048]^T (2 planes) -> fp32 out
    gemm8pv<<<256, 512, 98304, stream>>>(
        (const char*)p, (const char*)vT_hi, (const char*)vT_lo, out);
}

// Round 7
// 379.598 us; speedup vs baseline: 3.5044x; 1.0367x over previous
//
#include <hip/hip_runtime.h>
#include <hip/hip_bf16.h>

// Problem: B=4, S=2048, HIDDEN=ATTN=1024.
// q = query@Wq + bq ; v = value@Wv + bv ; sc = q@v^T ; p = softmax(sc) ; out = p@v
// All GEMMs bf16 hi/lo-split MFMA, 256-wide-tile pipelined kernels.
// R7: barrier-minimal K-step (2 barriers/step instead of 8); compiler-
// scheduled lgkm waits; B-reg caching retained; T1 XCD grid; T2 swizzle.

typedef unsigned short u16;
typedef __attribute__((ext_vector_type(8))) short bf16x8;  // 4 VGPRs
typedef __attribute__((ext_vector_type(4))) float f32x4;

typedef __attribute__((address_space(1))) void gvoid_t;
typedef __attribute__((address_space(3))) void svoid_t;

__device__ __forceinline__ void gll16(const void* g, void* l) {
    __builtin_amdgcn_global_load_lds((gvoid_t*)g, (svoid_t*)l, 16, 0, 0);
}

__device__ __forceinline__ u16 bf16rn(float x) {
    unsigned u = __float_as_uint(x);
    unsigned r = (u + 0x7FFFu + ((u >> 16) & 1u)) >> 16;
    return (u16)r;
}
__device__ __forceinline__ float bf2f(u16 h) {
    return __uint_as_float(((unsigned)h) << 16);
}

__device__ __forceinline__ const char* sel3(const char* p0, const char* p1,
                                            const char* p2, int i) {
    return i == 0 ? p0 : (i == 1 ? p1 : p2);
}

// ===========================================================================
// 256x256 NT GEMM, BK=64, 512 thr = 8 waves (2M x 4N), LDS 128 KiB.
// K' = 48 steps = 3 planes of 1024 (plane row stride fixed 2048 B).
// Step layout (2 barriers):
//   RD_A(0), RD_B(b0r,0); stage A1(s+1); Q(0,0)
//   RD_B(b1r,1);          stage B1(s+1); Q(0,1)
//   --- barrier (half-0 reads done; allow overwrite) ---
//   RD_A(1);              stage A0(s+2); Q(1,0)
//                         stage B0(s+2); Q(1,1)
//   VM4; --- barrier (step boundary) ---
// ===========================================================================
#define NSK 48

#define STAGE_A(T, mh) {                                                      \
    const char* _p = sel3(A0z, A1z, A2z, (T) >> 4) + (long)((T) & 15) * 128;  \
    char* _d = smem + (((T) & 1) << 16) + ((mh) << 14) + (w << 10);           \
    gll16(_p + offA##mh##0, _d);                                              \
    gll16(_p + offA##mh##1, _d + 8192); }

#define STAGE_B(T, nh) {                                                      \
    const char* _p = sel3(B0z, B1z, B2z, (T) >> 4) + (long)((T) & 15) * 128;  \
    char* _d = smem + (((T) & 1) << 16) + 32768 + ((nh) << 14) + (w << 10);   \
    gll16(_p + offB##nh##0, _d);                                              \
    gll16(_p + offB##nh##1, _d + 8192); }

#define VM4 { asm volatile("s_waitcnt vmcnt(4)" ::: "memory");                \
              __builtin_amdgcn_sched_barrier(0); }
#define VM0 { asm volatile("s_waitcnt vmcnt(0)" ::: "memory");                \
              __builtin_amdgcn_sched_barrier(0); }

#define RD_A(mh)                                                              \
    _Pragma("unroll") for (int mi = 0; mi < 4; ++mi)                          \
      _Pragma("unroll") for (int ks = 0; ks < 2; ++ks)                        \
        afr[mi][ks] = *(const bf16x8*)(smem + bufb + ((mh) << 14) +           \
            aRdB + mi * 2048 + csw[ks]);

#define RD_B(BFR, nh)                                                         \
    _Pragma("unroll") for (int ni = 0; ni < 2; ++ni)                          \
      _Pragma("unroll") for (int ks = 0; ks < 2; ++ks)                        \
        BFR[ni][ks] = *(const bf16x8*)(smem + bufb + ((nh) << 14) +           \
            bRdB + ni * 2048 + csw[ks]);

#define MFMA_Q(mh, nh, BFR) {                                                 \
    __builtin_amdgcn_s_setprio(1);                                            \
    _Pragma("unroll") for (int mi = 0; mi < 4; ++mi)                          \
      _Pragma("unroll") for (int ni = 0; ni < 2; ++ni)                        \
        _Pragma("unroll") for (int ks = 0; ks < 2; ++ks)                      \
          acc[(mh) * 4 + mi][(nh) * 2 + ni] =                                 \
              __builtin_amdgcn_mfma_f32_16x16x32_bf16(                        \
                  afr[mi][ks], BFR[ni][ks],                                   \
                  acc[(mh) * 4 + mi][(nh) * 2 + ni], 0, 0, 0);                \
    __builtin_amdgcn_s_setprio(0); }

template<bool OUTF32, int SCHEME>
__global__ __launch_bounds__(512, 2)
void gemm8(const char* a0, const char* a1, const char* a2, long zA,
           const char* b0, const char* b1, const char* b2, long zB,
           float* __restrict__ Of, u16* __restrict__ Ohi, u16* __restrict__ Olo,
           long zC, const float* __restrict__ bias0,
           const float* __restrict__ bias1, int N)
{
    extern __shared__ char smem[];
    const int t = threadIdx.x, lane = t & 63, w = t >> 6;
    const int wm = w >> 2, wn = w & 3;

    // T1: XCD-chunked decode (bid%8 = XCD round-robin assumption; perf-only)
    const int bid = blockIdx.x;
    const int xcd = bid & 7, bi = bid >> 3;
    int m0, n0, z;
    if (SCHEME == 0) {            // scores: x=8 N-tiles, y=8 M-tiles, z=4
        z = xcd >> 1;
        m0 = (((xcd & 1) << 2) | (bi >> 3)) << 8;
        n0 = (bi & 7) << 8;
    } else {                      // proj: x=4, y=32, z=2
        m0 = ((xcd << 2) | (bi >> 3)) << 8;
        n0 = (bi & 3) << 8;
        z = (bi >> 2) & 1;
    }

    const char* A0z = a0 + (long)z * zA;
    const char* A1z = a1 + (long)z * zA;
    const char* A2z = a2 + (long)z * zA;
    const char* B0z = b0 + (long)z * zB;
    const char* B1z = b1 + (long)z * zB;
    const char* B2z = b2 + (long)z * zB;

    // staging: LDS linear (lr, c) <- global (grow, c ^ ((lr&7)<<4))
    const int lr0 = t >> 3;
    const long cg = (long)((((t & 7) ^ ((t >> 3) & 7)) << 4));
    const long offA00 = (long)(m0 + lr0) * 2048 + cg;
    const long offA01 = offA00 + 128L * 2048;
    const long offA10 = (long)(m0 + 64 + lr0) * 2048 + cg;
    const long offA11 = offA10 + 128L * 2048;
    const long offB00 = (long)(n0 + ((lr0 >> 5) << 6) + (lr0 & 31)) * 2048 + cg;
    const long offB01 = offB00 + 128L * 2048;
    const long offB10 = offB00 + 32L * 2048;
    const long offB11 = offB10 + 128L * 2048;

    const int swl = (lane & 7) << 4;
    const int csw[2] = { (((lane >> 4) << 4)) ^ swl,
                         (((lane >> 4) << 4) + 64) ^ swl };
    const int aRdB = (wm * 64 + (lane & 15)) * 128;
    const int bRdB = 32768 + (wn * 32 + (lane & 15)) * 128;

    f32x4 acc[8][4];
#pragma unroll
    for (int i = 0; i < 8; ++i)
#pragma unroll
        for (int j = 0; j < 4; ++j) acc[i][j] = (f32x4)0.f;
    bf16x8 afr[4][2];
    bf16x8 b0r[2][2], b1r[2][2];

    STAGE_A(0, 0); STAGE_B(0, 0); STAGE_A(0, 1); STAGE_B(0, 1);
    STAGE_A(1, 0); STAGE_B(1, 0);
    asm volatile("s_waitcnt vmcnt(4)" ::: "memory");
    __builtin_amdgcn_sched_barrier(0);
    __builtin_amdgcn_s_barrier();

    for (int s = 0; s < NSK - 2; ++s) {
        const int bufb = (s & 1) << 16;
        RD_A(0); RD_B(b0r, 0);
        STAGE_A(s + 1, 1);
        MFMA_Q(0, 0, b0r);
        RD_B(b1r, 1);
        STAGE_B(s + 1, 1);
        MFMA_Q(0, 1, b1r);
        __builtin_amdgcn_s_barrier();
        RD_A(1);
        STAGE_A(s + 2, 0);
        MFMA_Q(1, 0, b0r);
        STAGE_B(s + 2, 0);
        MFMA_Q(1, 1, b1r);
        VM4;
        __builtin_amdgcn_s_barrier();
    }
    {   // s = NSK-2: stage only A1/B1 of last tile; drain fully at end
        const int bufb = ((NSK - 2) & 1) << 16;
        RD_A(0); RD_B(b0r, 0);
        STAGE_A(NSK - 1, 1);
        MFMA_Q(0, 0, b0r);
        RD_B(b1r, 1);
        STAGE_B(NSK - 1, 1);
        MFMA_Q(0, 1, b1r);
        RD_A(1);
        MFMA_Q(1, 0, b0r);
        MFMA_Q(1, 1, b1r);
        VM0;
        __builtin_amdgcn_s_barrier();
    }
    {   // s = NSK-1: compute only
        const int bufb = ((NSK - 1) & 1) << 16;
        RD_A(0); RD_B(b0r, 0);
        MFMA_Q(0, 0, b0r);
        RD_B(b1r, 1);
        MFMA_Q(0, 1, b1r);
        RD_A(1);
        MFMA_Q(1, 0, b0r);
        MFMA_Q(1, 1, b1r);
    }

    const int r0 = m0 + wm * 128 + ((lane >> 4) << 2);
    const int c0 = n0 + wn * 64 + (lane & 15);
    if (OUTF32) {
        float* Co = Of + (long)z * zC;
#pragma unroll
        for (int mi = 0; mi < 8; ++mi)
#pragma unroll
            for (int nj = 0; nj < 4; ++nj)
#pragma unroll
                for (int r = 0; r < 4; ++r)
                    Co[(long)(r0 + mi * 16 + r) * N + c0 + nj * 16] =
                        acc[mi][nj][r];
    } else {
        const float* bs = z ? bias1 : bias0;
        float bc[4];
#pragma unroll
        for (int nj = 0; nj < 4; ++nj) bc[nj] = bs[c0 + nj * 16];
        u16* Oh = Ohi + (long)z * zC;
        u16* Ol = Olo + (long)z * zC;
#pragma unroll
        for (int mi = 0; mi < 8; ++mi)
#pragma unroll
            for (int nj = 0; nj < 4; ++nj)
#pragma unroll
                for (int r = 0; r < 4; ++r) {
                    float x = acc[mi][nj][r] + bc[nj];
                    long o = (long)(r0 + mi * 16 + r) * N + c0 + nj * 16;
                    u16 h = bf16rn(x);
                    Oh[o] = h;
                    Ol[o] = bf16rn(x - bf2f(h));
                }
    }
}

// ===========================================================================
// PV: 256x128 NT GEMM, barrier-minimal step. A = probs [2048][2048] bf16,
// B = vT planes hi/lo [1024][2048] -> K' = 64 steps (0-31 hi, 32-63 lo).
// 8 waves 2M x 4N, wave-tile 128x32. LDS 96 KiB (2 x {A 32K, B 16K}).
// ===========================================================================
#define PVNSK 64

#define PV_STAGE_A(T, mh) {                                                   \
    const char* _p = Ap + (long)((T) & 31) * 128;                             \
    char* _d = smem + (((T) & 1) * 49152) + ((mh) << 14) + (w << 10);         \
    gll16(_p + offA##mh##0, _d);                                              \
    gll16(_p + offA##mh##1, _d + 8192); }

#define PV_STAGE_B(T, nh) {                                                   \
    const char* _p = (((T) >> 5) ? Bl : Bh) + (long)((T) & 31) * 128;         \
    char* _d = smem + (((T) & 1) * 49152) + 32768 + ((nh) << 13) + (w << 10); \
    gll16(_p + offB##nh, _d); }

#define PVM3 { asm volatile("s_waitcnt vmcnt(3)" ::: "memory");               \
               __builtin_amdgcn_sched_barrier(0); }

#define PV_RD_A(mh)                                                           \
    _Pragma("unroll") for (int mi = 0; mi < 4; ++mi)                          \
      _Pragma("unroll") for (int ks = 0; ks < 2; ++ks)                        \
        afr[mi][ks] = *(const bf16x8*)(smem + bufb + ((mh) << 14) +           \
            aRdB + mi * 2048 + csw[ks]);

#define PV_RD_B(BFR, nh)                                                      \
    _Pragma("unroll") for (int ks = 0; ks < 2; ++ks)                          \
      BFR[ks] = *(const bf16x8*)(smem + bufb + 32768 + ((nh) << 13) +         \
          bRdB + csw[ks]);

#define PV_MFMA_Q(mh, nh, BFR) {                                              \
    __builtin_amdgcn_s_setprio(1);                                            \
    _Pragma("unroll") for (int mi = 0; mi < 4; ++mi)                          \
      _Pragma("unroll") for (int ks = 0; ks < 2; ++ks)                        \
        acc[(mh) * 4 + mi][nh] =                                              \
            __builtin_amdgcn_mfma_f32_16x16x32_bf16(                          \
                afr[mi][ks], BFR[ks], acc[(mh) * 4 + mi][nh], 0, 0, 0);       \
    __builtin_amdgcn_s_setprio(0); }

__global__ __launch_bounds__(512, 2)
void gemm8pv(const char* pA, const char* vTh, const char* vTl,
             float* __restrict__ Of)
{
    extern __shared__ char smem[];
    const int t = threadIdx.x, lane = t & 63, w = t >> 6;
    const int wm = w >> 2, wn = w & 3;

    const int bid = blockIdx.x;
    const int xcd = bid & 7, bi = bid >> 3;
    const int z  = xcd >> 1;
    const int m0 = ((((xcd & 1) << 2) | (bi >> 3)) << 8);   // 8 M-tiles of 256
    const int n0 = (bi & 7) << 7;                           // 8 N-tiles of 128

    const char* Ap = pA  + (long)z * 8388608;   // 2048*2048*2B
    const char* Bh = vTh + (long)z * 4194304;   // 1024*2048*2B
    const char* Bl = vTl + (long)z * 4194304;

    const int lr0 = t >> 3;
    const long cg = (long)((((t & 7) ^ ((t >> 3) & 7)) << 4));
    const long offA00 = (long)(m0 + lr0) * 4096 + cg;        // row stride 2048 el
    const long offA01 = offA00 + 64L * 4096;
    const long offA10 = (long)(m0 + 128 + lr0) * 4096 + cg;
    const long offA11 = offA10 + 64L * 4096;
    const long offB0  = (long)(n0 + lr0) * 4096 + cg;
    const long offB1  = (long)(n0 + 64 + lr0) * 4096 + cg;

    const int swl = (lane & 7) << 4;
    const int csw[2] = { (((lane >> 4) << 4)) ^ swl,
                         (((lane >> 4) << 4) + 64) ^ swl };
    const int aRdB = (wm * 64 + (lane & 15)) * 128;
    const int bRdB = (wn * 16 + (lane & 15)) * 128;

    f32x4 acc[8][2];
#pragma unroll
    for (int i = 0; i < 8; ++i) { acc[i][0] = (f32x4)0.f; acc[i][1] = (f32x4)0.f; }
    bf16x8 afr[4][2];
    bf16x8 bA[2], bB[2];

    // prologue: tile0 (A0,A1,B0,B1 = 6 loads) + tile1 (A0,B0 = 3 loads)
    PV_STAGE_A(0, 0); PV_STAGE_B(0, 0); PV_STAGE_A(0, 1); PV_STAGE_B(0, 1);
    PV_STAGE_A(1, 0); PV_STAGE_B(1, 0);
    asm volatile("s_waitcnt vmcnt(3)" ::: "memory");
    __builtin_amdgcn_sched_barrier(0);
    __builtin_amdgcn_s_barrier();

    for (int s = 0; s < PVNSK - 2; ++s) {
        const int bufb = (s & 1) * 49152;
        PV_RD_A(0); PV_RD_B(bA, 0);
        PV_STAGE_A(s + 1, 1);
        PV_MFMA_Q(0, 0, bA);
        PV_RD_B(bB, 1);
        PV_STAGE_B(s + 1, 1);
        PV_MFMA_Q(0, 1, bB);
        __builtin_amdgcn_s_barrier();
        PV_RD_A(1);
        PV_STAGE_A(s + 2, 0);
        PV_MFMA_Q(1, 0, bA);
        PV_STAGE_B(s + 2, 0);
        PV_MFMA_Q(1, 1, bB);
        PVM3;
        __builtin_amdgcn_s_barrier();
    }
    {   // s = PVNSK-2
        const int bufb = ((PVNSK - 2) & 1) * 49152;
        PV_RD_A(0); PV_RD_B(bA, 0);
        PV_STAGE_A(PVNSK - 1, 1);
        PV_MFMA_Q(0, 0, bA);
        PV_RD_B(bB, 1);
        PV_STAGE_B(PVNSK - 1, 1);
        PV_MFMA_Q(0, 1, bB);
        PV_RD_A(1);
        PV_MFMA_Q(1, 0, bA);
        PV_MFMA_Q(1, 1, bB);
        VM0;
        __builtin_amdgcn_s_barrier();
    }
    {   // s = PVNSK-1
        const int bufb = ((PVNSK - 1) & 1) * 49152;
        PV_RD_A(0); PV_RD_B(bA, 0);
        PV_MFMA_Q(0, 0, bA);
        PV_RD_B(bB, 1);
        PV_MFMA_Q(0, 1, bB);
        PV_RD_A(1);
        PV_MFMA_Q(1, 0, bA);
        PV_MFMA_Q(1, 1, bB);
    }

    float* Co = Of + (long)z * 2097152;
    const int r0 = m0 + wm * 64 + ((lane >> 4) << 2);
    const int c0 = n0 + wn * 16 + (lane & 15);
#pragma unroll
    for (int mh = 0; mh < 2; ++mh)
#pragma unroll
        for (int mi = 0; mi < 4; ++mi)
#pragma unroll
            for (int nh = 0; nh < 2; ++nh)
#pragma unroll
                for (int r = 0; r < 4; ++r)
                    Co[(long)(r0 + mh * 128 + mi * 16 + r) * 1024 +
                       c0 + nh * 64] = acc[mh * 4 + mi][nh][r];
}

// ---------------------------------------------------------------------------
// merged fp32 -> bf16 hi/lo split for query+value. grid (8192, 2).
// ---------------------------------------------------------------------------
__global__ __launch_bounds__(256)
void split2_f32(const float* __restrict__ q, const float* __restrict__ v,
                u16* __restrict__ qh, u16* __restrict__ ql,
                u16* __restrict__ vh, u16* __restrict__ vl)
{
    const int sel = blockIdx.y;
    const float* in = sel ? v : q;
    u16* hi = sel ? vh : qh;
    u16* lo = sel ? vl : ql;
    long i = ((long)blockIdx.x * 256 + threadIdx.x) * 4;
    float4 x = *(const float4*)(in + i);
    ushort4 h, l;
    h.x = bf16rn(x.x); l.x = bf16rn(x.x - bf2f(h.x));
    h.y = bf16rn(x.y); l.y = bf16rn(x.y - bf2f(h.y));
    h.z = bf16rn(x.z); l.z = bf16rn(x.z - bf2f(h.z));
    h.w = bf16rn(x.w); l.w = bf16rn(x.w - bf2f(h.w));
    *(ushort4*)(hi + i) = h;
    *(ushort4*)(lo + i) = l;
}

// merged W transpose+split: grid (32, 32, 2); z picks Wq/Wv.
__global__ __launch_bounds__(256)
void tsplit2_w(const float* __restrict__ Wq, const float* __restrict__ Wv,
               u16* __restrict__ qhi, u16* __restrict__ qlo,
               u16* __restrict__ vhi, u16* __restrict__ vlo)
{
    __shared__ float tile[32][33];
    const int sel = blockIdx.z;
    const float* W = sel ? Wv : Wq;
    u16* hi = sel ? vhi : qhi;
    u16* lo = sel ? vlo : qlo;
    const int n0v = blockIdx.x * 32, k0 = blockIdx.y * 32;
    const int r = threadIdx.x >> 5, c = threadIdx.x & 31;
#pragma unroll
    for (int it = 0; it < 4; ++it)
        tile[r + it * 8][c] = W[(long)(k0 + r + it * 8) * 1024 + n0v + c];
    __syncthreads();
#pragma unroll
    for (int it = 0; it < 4; ++it) {
        const int rr = r + it * 8;
        float x = tile[c][rr];
        u16 h = bf16rn(x);
        long o = (long)(n0v + rr) * 1024 + k0 + c;
        hi[o] = h;
        lo[o] = bf16rn(x - bf2f(h));
    }
}

// merged vectorized transpose: z = batch*2 + plane; v[s][d] -> vT[d][s]
__global__ __launch_bounds__(256)
void tr2_bf16(const u16* __restrict__ v_hi, const u16* __restrict__ v_lo,
              u16* __restrict__ vT_hi, u16* __restrict__ vT_lo)
{
    __shared__ u16 tile[64][68];
    const int pl = blockIdx.z & 1, b = blockIdx.z >> 1;
    const u16* src = (pl ? v_lo : v_hi) + (long)b * 2097152;
    u16* dst = (pl ? vT_lo : vT_hi) + (long)b * 2097152;
    const int s0 = blockIdx.x * 64, d0 = blockIdx.y * 64;
    const int t = threadIdx.x;
    const int rr = t >> 4, c4 = (t & 15) * 4;
#pragma unroll
    for (int it = 0; it < 4; ++it) {
        const int s = it * 16 + rr;
        *(short4*)&tile[s][c4] =
            *(const short4*)(src + (long)(s0 + s) * 1024 + d0 + c4);
    }
    __syncthreads();
#pragma unroll
    for (int it = 0; it < 4; ++it) {
        const int d = it * 16 + rr;
        short4 o;
        o.x = tile[c4 + 0][d]; o.y = tile[c4 + 1][d];
        o.z = tile[c4 + 2][d]; o.w = tile[c4 + 3][d];
        *(short4*)(dst + (long)(d0 + d) * 2048 + s0 + c4) = o;
    }
}

__global__ __launch_bounds__(256)
void softmax_p(const float* __restrict__ S, u16* __restrict__ P)
{
    const float* p = S + (long)blockIdx.x * 2048;
    u16* o = P + (long)blockIdx.x * 2048;
    const int t = threadIdx.x;

    float4 x0 = *(const float4*)&p[t * 4];
    float4 x1 = *(const float4*)&p[1024 + t * 4];

    float mx = fmaxf(fmaxf(fmaxf(x0.x, x0.y), fmaxf(x0.z, x0.w)),
                     fmaxf(fmaxf(x1.x, x1.y), fmaxf(x1.z, x1.w)));
#pragma unroll
    for (int off = 32; off; off >>= 1) mx = fmaxf(mx, __shfl_xor(mx, off));

    __shared__ float red[8];
    if ((t & 63) == 0) red[t >> 6] = mx;
    __syncthreads();
    mx = fmaxf(fmaxf(red[0], red[1]), fmaxf(red[2], red[3]));

    x0.x = __expf(x0.x - mx); x0.y = __expf(x0.y - mx);
    x0.z = __expf(x0.z - mx); x0.w = __expf(x0.w - mx);
    x1.x = __expf(x1.x - mx); x1.y = __expf(x1.y - mx);
    x1.z = __expf(x1.z - mx); x1.w = __expf(x1.w - mx);

    float sm2 = (x0.x + x0.y + x0.z + x0.w) + (x1.x + x1.y + x1.z + x1.w);
#pragma unroll
    for (int off = 32; off; off >>= 1) sm2 += __shfl_xor(sm2, off);
    if ((t & 63) == 0) red[4 + (t >> 6)] = sm2;
    __syncthreads();
    sm2 = (red[4] + red[5]) + (red[6] + red[7]);

    const float inv = 1.0f / sm2;
    ushort4 y;
    y.x = bf16rn(x0.x * inv); y.y = bf16rn(x0.y * inv);
    y.z = bf16rn(x0.z * inv); y.w = bf16rn(x0.w * inv);
    *(ushort4*)(o + t * 4) = y;
    y.x = bf16rn(x1.x * inv); y.y = bf16rn(x1.y * inv);
    y.z = bf16rn(x1.z * inv); y.w = bf16rn(x1.w * inv);
    *(ushort4*)(o + 1024 + t * 4) = y;
}

// ---------------------------------------------------------------------------
// ws layout (MiB): [0,64) qx_hi,qx_lo,vx_hi,vx_lo (16 each) -> later sc fp32;
// [64,96) q_hi,q_lo -> later p bf16; [96,128) v_hi,v_lo; [128,160) vT_hi,vT_lo;
// [160,168) WqT_hi,WqT_lo,WvT_hi,WvT_lo. Total 168 MB.
// ---------------------------------------------------------------------------
extern "C" void kernel_launch(void* const* d_in, const int* in_sizes, int n_in,
                              void* d_out, int out_size, void* d_ws, size_t ws_size,
                              hipStream_t stream)
{
    const float* query = (const float*)d_in[0];
    const float* value = (const float*)d_in[1];
    const float* Wq    = (const float*)d_in[2];
    const float* bq    = (const float*)d_in[3];
    const float* Wv    = (const float*)d_in[4];
    const float* bv    = (const float*)d_in[5];
    float* out = (float*)d_out;

    char* W = (char*)d_ws;
    u16* qx_hi = (u16*)(W);
    u16* qx_lo = qx_hi + 8388608;
    u16* vx_hi = qx_lo + 8388608;
    u16* vx_lo = vx_hi + 8388608;
    float* sc  = (float*)W;                       // overlaps qx/vx (dead by then)
    u16* q_hi  = (u16*)(W + 67108864);
    u16* q_lo  = q_hi + 8388608;
    u16* p     = (u16*)(W + 67108864);            // overlaps q_hi/q_lo (dead by then)
    u16* v_hi  = (u16*)(W + 100663296);
    u16* v_lo  = v_hi + 8388608;
    u16* vT_hi = (u16*)(W + 134217728);
    u16* vT_lo = vT_hi + 8388608;
    u16* WqT_hi = (u16*)(W + 167772160);
    u16* WqT_lo = WqT_hi + 1048576;
    u16* WvT_hi = WqT_lo + 1048576;
    u16* WvT_lo = WvT_hi + 1048576;

    hipFuncSetAttribute((const void*)&gemm8<false, 1>,
                        hipFuncAttributeMaxDynamicSharedMemorySize, 131072);
    hipFuncSetAttribute((const void*)&gemm8<true, 0>,
                        hipFuncAttributeMaxDynamicSharedMemorySize, 131072);
    hipFuncSetAttribute((const void*)&gemm8pv,
                        hipFuncAttributeMaxDynamicSharedMemorySize, 98304);

    // input splits (merged launches)
    split2_f32<<<dim3(8192, 2), 256, 0, stream>>>(query, value,
                                                  qx_hi, qx_lo, vx_hi, vx_lo);
    tsplit2_w<<<dim3(32, 32, 2), 256, 0, stream>>>(Wq, Wv,
                                                   WqT_hi, WqT_lo, WvT_hi, WvT_lo);

    // fused projections (z=0: q, z=1: v): planes A=[x_hi,x_hi,x_lo],
    // B=[W_hi,W_lo,W_hi]; out bf16 hi/lo (+bias)
    gemm8<false, 1><<<256, 512, 131072, stream>>>(
        (const char*)qx_hi, (const char*)qx_hi, (const char*)qx_lo, 33554432L,
        (const char*)WqT_hi, (const char*)WqT_lo, (const char*)WqT_hi, 4194304L,
        nullptr, q_hi, q_lo, 16777216L, bq, bv, 1024);

    // v^T (both planes, one launch)
    tr2_bf16<<<dim3(32, 16, 8), 256, 0, stream>>>(v_hi, v_lo, vT_hi, vT_lo);

    // scores: per batch, planes A=[q_hi,q_hi,q_lo], B=[v_hi,v_lo,v_hi] -> fp32
    gemm8<true, 0><<<256, 512, 131072, stream>>>(
        (const char*)q_hi, (const char*)q_hi, (const char*)q_lo, 4194304L,
        (const char*)v_hi, (const char*)v_lo, (const char*)v_hi, 4194304L,
        sc, nullptr, nullptr, 4194304L, nullptr, nullptr, 2048);

    softmax_p<<<8192, 256, 0, stream>>>(sc, p);

    // context: per batch [2048,2048] @ [1024,2048]^T (2 planes) -> fp32 out
    gemm8pv<<<256, 512, 98304, stream>>>(
        (const char*)p, (const char*)vT_hi, (const char*)vT_lo, out);
}